// Round 17
// baseline (272.211 us; speedup 1.0000x reference)
//
#include <hip/hip_runtime.h>

#define N_ 4096
#define DIM_ 512
#define H_ 8
#define DH_ 64
#define M_ 266
#define MP_ 272      // ksum/qp live range padded to 272 (17 tiles of 16)
#define MP2_ 288     // out-GEMM K padded to 9 chunks of 32
#define MP3_ 320     // ksuma / projp m padded to 5 chunks of 64
#define SLABM_ 280   // ctx partial-slab m extent (>= M_=266, trimmed to fit overlay)
#define NZ_ 8        // n-split for ctxfused
#define NT_ 16384
#define BH_ 32

#define NORMC 0.3535533905932738f   // 64^-0.25
#define RATIOC 0.06131393394849658f // 266^-0.5
#define EPSK 1e-4f
#define DIAGC 0.0625f               // 0.5 * normalizer^2
// folded exp2 constants: qp = exp2(min(raw*KA + Cl, LOG2R)) + REPS
#define KA 0.51006971f              // NORMC * log2(e)
#define LOG2R -4.0276408f           // log2(RATIOC)
#define LOG2E 1.4426950408889634f
#define REPS 6.131393e-6f           // RATIOC * EPSK

// ---- ws layout (byte offsets), total ~71.5 MB ----
// ctx slabs (18,350,080 B) overlay xbf+wqb+wkb+wvb, dead after qkv_mfma.
#define PROJP_B 0ul            // 40960
#define KMAX_B  40960ul        // 128
#define KSUMA_B 41088ul        // 40960
#define WO_B    82048ul        // 524288
#define CTXT_B  606336ul       // 1179648
#define DIAGQ_B 1785984ul      // 262144
#define DIAGK_B 2048128ul      // 262144
#define XBF_B   2310272ul      // 16777216
#define WQ_B    19087488ul     // 524288
#define WK_B    19611776ul     // 524288
#define WV_B    20136064ul     // 524288
#define CTXA_B  2310272ul      // == XBF_B, 32*8*280*64*4 = 18350080 (ends at Q_B)
#define Q_B     20660352ul     // 16777216
#define K_B     37437568ul     // 16777216
#define VT_B    54214784ul     // 16777216
#define RMAXQ_B 70992000ul     // 524288 (32*4096 f32) -> end 71,516,288

typedef __bf16 bf16x8 __attribute__((ext_vector_type(8)));
typedef float f32x4 __attribute__((ext_vector_type(4)));
#define MFMA16(a, b, c) __builtin_amdgcn_mfma_f32_16x16x32_bf16((a), (b), (c), 0, 0, 0)

// async global->LDS, 16B per lane; LDS dest = wave-uniform base + lane*16
typedef __attribute__((address_space(1))) const unsigned int* gas_t;
typedef __attribute__((address_space(3))) unsigned int* las_t;
__device__ __forceinline__ void gload16(const void* g, void* l) {
  __builtin_amdgcn_global_load_lds((gas_t)g, (las_t)l, 16, 0, 0);
}

__device__ __forceinline__ float bfu(unsigned short u) {
  union { unsigned int i; float f; } x; x.i = ((unsigned int)u) << 16; return x.f;
}
__device__ __forceinline__ unsigned short f2bf(float f) {
  union { float f; unsigned int i; } u; u.f = f;
  unsigned int r = u.i + 0x7fffu + ((u.i >> 16) & 1u);
  return (unsigned short)(r >> 16);
}
__device__ __forceinline__ void atomicMaxF(float* addr, float val) {
  int* ai = (int*)addr;
  while (true) {
    float cur = __int_as_float(*(volatile int*)ai);
    if (val <= cur) break;
    int old = atomicCAS(ai, __float_as_int(cur), __float_as_int(val));
    if (old == __float_as_int(cur)) break;
  }
}

// ---------------- prep: all fp32->bf16 conversions + proj pad + inits (1 launch) ----------------
__global__ void prep_kernel(const float* __restrict__ x, const float* __restrict__ Wq,
                            const float* __restrict__ Wk, const float* __restrict__ Wv,
                            const float* __restrict__ Wo, const float* __restrict__ proj,
                            unsigned short* __restrict__ xbf, unsigned short* __restrict__ wqb,
                            unsigned short* __restrict__ wkb, unsigned short* __restrict__ wvb,
                            unsigned short* __restrict__ wob,
                            unsigned short* __restrict__ projp,
                            float* __restrict__ kmax, float* __restrict__ ksuma) {
  const int t0 = blockIdx.x * 256 + threadIdx.x;
  const int stride = gridDim.x * 256;
  for (int i = t0; i < 8388608 / 4; i += stride) {
    const float4 v = ((const float4*)x)[i];
    ushort4 u;
    u.x = f2bf(v.x); u.y = f2bf(v.y); u.z = f2bf(v.z); u.w = f2bf(v.w);
    ((ushort4*)xbf)[i] = u;
  }
  const float* wsrc[4] = {Wq, Wk, Wv, Wo};
  unsigned short* wdst[4] = {wqb, wkb, wvb, wob};
#pragma unroll
  for (int w = 0; w < 4; ++w) {
    for (int i = t0; i < 262144 / 4; i += stride) {
      const float4 v = ((const float4*)wsrc[w])[i];
      ushort4 u;
      u.x = f2bf(v.x); u.y = f2bf(v.y); u.z = f2bf(v.z); u.w = f2bf(v.w);
      ((ushort4*)wdst[w])[i] = u;
    }
  }
  for (int j = t0; j < MP3_ * DH_; j += stride)
    projp[j] = (j < M_ * DH_) ? f2bf(proj[j]) : (unsigned short)0;
  for (int j = t0; j < BH_; j += stride) kmax[j] = -3e38f;
  for (int j = t0; j < BH_ * MP3_; j += stride) ksuma[j] = 0.f;
}

// ---------------- QKV projection: 128x128 MFMA GEMM, global_load_lds staging ----------------
// r7/r11-proven local optimum; z passed as ARG (3 dispatches) for profile visibility.
__global__ __launch_bounds__(256) void qkv_mfma(
    const unsigned short* __restrict__ x, const unsigned short* __restrict__ W,
    unsigned short* __restrict__ dstQK,  // Q (z=0) or K (z=1); unused for z=2
    unsigned short* __restrict__ VT,     // used for z=2
    const int z) {
  __shared__ unsigned short As[128 * 64];
  __shared__ unsigned short Bs[128 * 64];
  const int t0 = blockIdx.x * 128, e0 = blockIdx.y * 128;
  const int tid = threadIdx.x;
  const int wv = tid >> 6, lane = tid & 63;
  const int r = lane & 15, q = lane >> 4;
  const int wr = (wv >> 1) * 64, wc = (wv & 1) * 64;
  f32x4 acc[4][4];
#pragma unroll
  for (int i = 0; i < 4; ++i)
#pragma unroll
    for (int j = 0; j < 4; ++j) acc[i][j] = (f32x4){0.f, 0.f, 0.f, 0.f};
  // staging: wave wv covers rows wv*32 + j*8 + (lane>>3), col (lane&7)*8
  const int lrow = lane >> 3, lcol = (lane & 7) * 8;
  for (int k0 = 0; k0 < DIM_; k0 += 64) {
#pragma unroll
    for (int j = 0; j < 4; ++j) {
      const int rr = wv * 32 + j * 8;
      gload16(&x[(size_t)(t0 + rr + lrow) * DIM_ + k0 + lcol], &As[rr * 64]);
      gload16(&W[(size_t)(e0 + rr + lrow) * DIM_ + k0 + lcol], &Bs[rr * 64]);
    }
    __syncthreads();
#pragma unroll
    for (int kc = 0; kc < 2; ++kc) {
      bf16x8 af[4], bfr[4];
#pragma unroll
      for (int rt = 0; rt < 4; ++rt)
        af[rt] = *(const bf16x8*)&As[(wr + rt * 16 + r) * 64 + kc * 32 + q * 8];
#pragma unroll
      for (int ct = 0; ct < 4; ++ct)
        bfr[ct] = *(const bf16x8*)&Bs[(wc + ct * 16 + r) * 64 + kc * 32 + q * 8];
#pragma unroll
      for (int rt = 0; rt < 4; ++rt)
#pragma unroll
        for (int ct = 0; ct < 4; ++ct)
          acc[rt][ct] = MFMA16(af[rt], bfr[ct], acc[rt][ct]);
    }
    __syncthreads();
  }
  if (z < 2) {
    unsigned short* dst = dstQK;
#pragma unroll
    for (int rt = 0; rt < 4; ++rt) {
#pragma unroll
      for (int ct = 0; ct < 4; ++ct) {
        const int e = e0 + wc + ct * 16 + r;
#pragma unroll
        for (int i = 0; i < 4; ++i) {
          const int t = t0 + wr + rt * 16 + q * 4 + i;
          dst[(size_t)t * DIM_ + e] = f2bf(acc[rt][ct][i]);
        }
      }
    }
  } else {
#pragma unroll
    for (int rt = 0; rt < 4; ++rt) {
      const int t = t0 + wr + rt * 16 + q * 4;
      const int b_ = t >> 12, n = t & (N_ - 1);
#pragma unroll
      for (int ct = 0; ct < 4; ++ct) {
        const int e = e0 + wc + ct * 16 + r;
        const int h = e >> 6, dh = e & 63;
        ushort4 pk;
        pk.x = f2bf(acc[rt][ct][0]); pk.y = f2bf(acc[rt][ct][1]);
        pk.z = f2bf(acc[rt][ct][2]); pk.w = f2bf(acc[rt][ct][3]);
        *(ushort4*)&VT[((size_t)((b_ * H_ + h) * DH_ + dh)) * N_ + n] = pk;
      }
    }
  }
}

// ---------------- kmax/qmax (MFMA, merged) + diag: K global max, Q per-row max, diag_q/k ----------------
__global__ __launch_bounds__(256) void kmax_mfma(
    const unsigned short* __restrict__ K, const unsigned short* __restrict__ Qb,
    const unsigned short* __restrict__ projp,
    float* __restrict__ kmax, float* __restrict__ rmaxq,
    unsigned short* __restrict__ dq, unsigned short* __restrict__ dk) {
  __shared__ unsigned short sP[MP_][72];
  __shared__ float wm[4];
  const int bh = blockIdx.x, n0 = blockIdx.y * 256;
  const int tid = threadIdx.x;
  const int wv = tid >> 6, lane = tid & 63;
  const int r = lane & 15, q = lane >> 4;
  const int b_ = bh >> 3, h = bh & 7;
  // stage proj rows 0..271 (coalesced 16B chunks)
  for (int c = tid; c < MP_ * 4; c += 256) {
    const int row = c >> 2, cb = (c & 3) * 8;
    *(uint4*)&sP[row][cb] = *(const uint4*)&projp[row * DH_ + cb];
  }
  // load 4 K-strips + 4 Q-strips: rows nbase + st*16 + r
  bf16x8 kb[4][2], qb[4][2];
  const int nbase = n0 + wv * 64;
#pragma unroll
  for (int st = 0; st < 4; ++st) {
    const size_t off = (size_t)(b_ * N_ + nbase + st * 16 + r) * DIM_ + h * DH_;
    kb[st][0] = *(const bf16x8*)(K + off + q * 8);
    kb[st][1] = *(const bf16x8*)(K + off + 32 + q * 8);
    qb[st][0] = *(const bf16x8*)(Qb + off + q * 8);
    qb[st][1] = *(const bf16x8*)(Qb + off + 32 + q * 8);
  }
  // diag (merged): each lane holds 16 of the row's 64 values; q-butterfly completes the sum
#pragma unroll
  for (int st = 0; st < 4; ++st) {
    float sk = 0.f, sq = 0.f;
#pragma unroll
    for (int p = 0; p < 2; ++p)
#pragma unroll
      for (int e = 0; e < 8; ++e) {
        const float kv = (float)kb[st][p][e];
        const float qv = (float)qb[st][p][e];
        sk += kv * kv;
        sq += qv * qv;
      }
    sk += __shfl_xor(sk, 16, 64); sk += __shfl_xor(sk, 32, 64);
    sq += __shfl_xor(sq, 16, 64); sq += __shfl_xor(sq, 32, 64);
    if (q == 0) {
      dk[bh * N_ + nbase + st * 16 + r] = f2bf(sk * DIAGC);
      dq[bh * N_ + nbase + st * 16 + r] = f2bf(sq * DIAGC);
    }
  }
  __syncthreads();
  float km = -3e38f;
  float qm[4] = {-3e38f, -3e38f, -3e38f, -3e38f};
  for (int mt = 0; mt < 17; ++mt) {
    const bf16x8 p0 = *(const bf16x8*)&sP[mt * 16 + r][q * 8];
    const bf16x8 p1 = *(const bf16x8*)&sP[mt * 16 + r][32 + q * 8];
#pragma unroll
    for (int st = 0; st < 4; ++st) {
      f32x4 ka = (f32x4){0.f, 0.f, 0.f, 0.f};
      ka = MFMA16(p0, kb[st][0], ka);
      ka = MFMA16(p1, kb[st][1], ka);
      f32x4 qa = (f32x4){0.f, 0.f, 0.f, 0.f};
      qa = MFMA16(p0, qb[st][0], qa);
      qa = MFMA16(p1, qb[st][1], qa);
#pragma unroll
      for (int i = 0; i < 4; ++i) {
        const int m = mt * 16 + q * 4 + i;
        if (m < M_) {
          km = fmaxf(km, ka[i]);
          qm[st] = fmaxf(qm[st], qa[i]);
        }
      }
    }
  }
  // Q: per-row raw max -- combine the 4 q-groups (m coverage) per row
#pragma unroll
  for (int st = 0; st < 4; ++st) {
    float v = qm[st];
    v = fmaxf(v, __shfl_xor(v, 16, 64));
    v = fmaxf(v, __shfl_xor(v, 32, 64));
    if (q == 0) rmaxq[bh * N_ + nbase + st * 16 + r] = v;
  }
  // K: block max -> atomic
  for (int s2 = 1; s2 < 64; s2 <<= 1) km = fmaxf(km, __shfl_xor(km, s2, 64));
  if (lane == 0) wm[wv] = km;
  __syncthreads();
  if (tid == 0) {
    const float m = fmaxf(fmaxf(wm[0], wm[1]), fmaxf(wm[2], wm[3])) * NORMC;
    atomicMaxF(&kmax[bh], m);
  }
}

// ---------------- fused: td -> exp -> kp; ctx += kp x VT; ksum ----------------
// global_load_lds staging into LINEAR [64][64] kll/vtl; swapped-operand kp MFMA;
// packed kpl writes; exp2-folded constants.
__global__ __launch_bounds__(256) void ctxfused_mfma(
    const unsigned short* __restrict__ K, const unsigned short* __restrict__ VT,
    const unsigned short* __restrict__ projp, const unsigned short* __restrict__ diag_k,
    const float* __restrict__ kmaxv, float* __restrict__ ksuma,
    float* __restrict__ slab) {
  __shared__ unsigned short kll[64][64];
  __shared__ unsigned short vtl[64][64];
  __shared__ unsigned short kpl[64][72];
  __shared__ float dglC[64];
  const int bh = blockIdx.x, m0 = blockIdx.y * 64, zi = blockIdx.z;
  const int nbase = zi * 512;
  const int tid = threadIdx.x;
  const int wv = tid >> 6, lane = tid & 63;
  const int r = lane & 15, q = lane >> 4;
  const int b_ = bh >> 3, h = bh & 7;
  const float km = kmaxv[bh];
  const int m = m0 + wv * 16 + r;          // this lane's kp row
  const float msk = (m < M_) ? 1.f : 0.f;
  const unsigned short* prow = projp + (size_t)m * DH_;
  const bf16x8 p0 = *(const bf16x8*)(prow + q * 8);
  const bf16x8 p1 = *(const bf16x8*)(prow + 32 + q * 8);
  const unsigned short* kbase = K + (size_t)(b_ * N_) * DIM_ + h * DH_;
  const unsigned short* vbase = VT + (size_t)bh * DH_ * N_;
  f32x4 cacc[4];
#pragma unroll
  for (int i = 0; i < 4; ++i) cacc[i] = (f32x4){0.f, 0.f, 0.f, 0.f};
  float ksa = 0.f;
  // gload16 lane mapping: row base+l/8, elem col (l&7)*8 (rows are 128B linear)
  const int srow = lane >> 3, scol = (lane & 7) * 8;
  for (int nc = 0; nc < 8; ++nc) {
    const int n0c = nbase + nc * 64;
#pragma unroll
    for (int j = 0; j < 2; ++j) {
      const int rb = wv * 16 + j * 8;   // wave-uniform row base, 8 rows per issue
      gload16(&kbase[(size_t)(n0c + rb + srow) * DIM_ + scol], &kll[rb][0]);
      gload16(&vbase[(size_t)(rb + srow) * N_ + n0c + scol], &vtl[rb][0]);
    }
    if (tid < 16) {
      const ushort4 du = *(const ushort4*)&diag_k[bh * N_ + n0c + tid * 4];
      dglC[tid * 4 + 0] = LOG2R - (bfu(du.x) + km) * LOG2E;
      dglC[tid * 4 + 1] = LOG2R - (bfu(du.y) + km) * LOG2E;
      dglC[tid * 4 + 2] = LOG2R - (bfu(du.z) + km) * LOG2E;
      dglC[tid * 4 + 3] = LOG2R - (bfu(du.w) + km) * LOG2E;
    }
    __syncthreads();
#pragma unroll
    for (int nt = 0; nt < 4; ++nt) {
      const bf16x8 kb0 = *(const bf16x8*)&kll[nt * 16 + r][q * 8];
      const bf16x8 kb1 = *(const bf16x8*)&kll[nt * 16 + r][32 + q * 8];
      f32x4 acc = (f32x4){0.f, 0.f, 0.f, 0.f};
      acc = MFMA16(kb0, p0, acc);   // swapped: lane holds n = nt*16+q*4+i at m = wv*16+r
      acc = MFMA16(kb1, p1, acc);
      const f32x4 cl = *(const f32x4*)&dglC[nt * 16 + q * 4];
      float e0, e1, e2, e3;
      {
        const float s0 = fminf(acc[0] * KA + cl[0], LOG2R);
        const float s1 = fminf(acc[1] * KA + cl[1], LOG2R);
        const float s2 = fminf(acc[2] * KA + cl[2], LOG2R);
        const float s3 = fminf(acc[3] * KA + cl[3], LOG2R);
        e0 = msk * (exp2f(s0) + REPS);
        e1 = msk * (exp2f(s1) + REPS);
        e2 = msk * (exp2f(s2) + REPS);
        e3 = msk * (exp2f(s3) + REPS);
      }
      ksa += (e0 + e1) + (e2 + e3);
      unsigned int w0, w1;
      asm("v_cvt_pk_bf16_f32 %0, %1, %2" : "=v"(w0) : "v"(e0), "v"(e1));
      asm("v_cvt_pk_bf16_f32 %0, %1, %2" : "=v"(w1) : "v"(e2), "v"(e3));
      *(uint2*)&kpl[wv * 16 + r][nt * 16 + q * 4] = make_uint2(w0, w1);
    }
    __syncthreads();
    {
      const bf16x8 a0 = *(const bf16x8*)&kpl[wv * 16 + r][q * 8];
      const bf16x8 a1 = *(const bf16x8*)&kpl[wv * 16 + r][32 + q * 8];
#pragma unroll
      for (int ct = 0; ct < 4; ++ct) {
        const bf16x8 b0 = *(const bf16x8*)&vtl[ct * 16 + r][q * 8];
        const bf16x8 b1 = *(const bf16x8*)&vtl[ct * 16 + r][32 + q * 8];
        cacc[ct] = MFMA16(a0, b0, cacc[ct]);
        cacc[ct] = MFMA16(a1, b1, cacc[ct]);
      }
    }
    __syncthreads();
  }
  // ksa: lane holds partial over n in its q-group -> butterfly over q bits
  ksa += __shfl_xor(ksa, 16, 64);
  ksa += __shfl_xor(ksa, 32, 64);
  if (q == 0) atomicAdd(&ksuma[bh * MP3_ + m], ksa);
  float* sl = slab + (size_t)(bh * NZ_ + zi) * SLABM_ * DH_;
#pragma unroll
  for (int ct = 0; ct < 4; ++ct) {
#pragma unroll
    for (int i = 0; i < 4; ++i) {
      const int mm = m0 + wv * 16 + q * 4 + i;
      if (mm < SLABM_) sl[(size_t)mm * DH_ + ct * 16 + r] = cacc[ct][i];
    }
  }
}

// ---------------- pack: reduce 8 z-slabs [m][d] fp32 -> transpose -> ctxT [d][288] bf16 ----
__global__ __launch_bounds__(256) void pack_kernel(const float* __restrict__ slab,
                                                   unsigned short* __restrict__ ctxT) {
  __shared__ float t[64][65];
  const int bh = blockIdx.x, m0 = blockIdx.y * 64;
  const int tid = threadIdx.x;
  const int mr = tid >> 4, d4 = (tid & 15) * 4;
#pragma unroll
  for (int pass = 0; pass < 4; ++pass) {
    const int ml = pass * 16 + mr;
    const int m = m0 + ml;
    float4 s = {0.f, 0.f, 0.f, 0.f};
    if (m < SLABM_) {
#pragma unroll
      for (int z = 0; z < NZ_; ++z) {
        const float4 v =
            *(const float4*)&slab[((size_t)(bh * NZ_ + z) * SLABM_ + m) * DH_ + d4];
        s.x += v.x; s.y += v.y; s.z += v.z; s.w += v.w;
      }
    }
    t[ml][d4 + 0] = s.x; t[ml][d4 + 1] = s.y; t[ml][d4 + 2] = s.z; t[ml][d4 + 3] = s.w;
  }
  __syncthreads();
  const int mc = tid & 63, dbase = tid >> 6;
  const int mo = m0 + mc;
  if (mo < MP2_) {
#pragma unroll
    for (int j = 0; j < 16; ++j) {
      const int d = dbase + j * 4;
      ctxT[((size_t)bh * DH_ + d) * MP2_ + mo] = f2bf(t[mc][d]);
    }
  }
}

// ---------------- fused QP + out GEMM: LDS-staged proj (time-shared with qp tile) ----------------
// VALU cuts: denominator from UNROUNDED e (reference never rounds qp; deletes the
// unpack), epilogue via v_cvt_pk_bf16_f32 pairs (same RNE rounding as f2bf).
__global__ __launch_bounds__(256) void qpout_mfma(
    const unsigned short* __restrict__ Qb, const unsigned short* __restrict__ projp,
    const float* __restrict__ rmaxq,
    const unsigned short* __restrict__ diag_q, const float* __restrict__ ksuma,
    const unsigned short* __restrict__ ctxT, unsigned short* __restrict__ attn) {
  __shared__ union SM {
    unsigned short sP[MP_][72];      // 39168 B  (phase B)
    unsigned int qps[4][16][149];    // 38144 B  (phase C; per-wave tile, stride 149 u32)
  } sm;
  const int bh = blockIdx.x, n0 = blockIdx.y * 64;
  const int tid = threadIdx.x;
  const int wv = tid >> 6, lane = tid & 63;
  const int r = lane & 15, q = lane >> 4;
  const int b_ = bh >> 3, h = bh & 7;
  // stage proj rows 0..271 into sP (coalesced 16B chunks)
  for (int c = tid; c < MP_ * 4; c += 256) {
    const int row = c >> 2, cb = (c & 3) * 8;
    *(uint4*)&sm.sP[row][cb] = *(const uint4*)&projp[row * DH_ + cb];
  }
  bf16x8 qb0, qb1;
  {
    const unsigned short* qrow = Qb + (size_t)(b_ * N_ + n0 + wv * 16 + r) * DIM_ + h * DH_;
    qb0 = *(const bf16x8*)(qrow + q * 8);
    qb1 = *(const bf16x8*)(qrow + 32 + q * 8);
  }
  const float rm = rmaxq[bh * N_ + n0 + wv * 16 + r];
  const float dg = bfu(diag_q[bh * N_ + n0 + wv * 16 + r]);
  const float Cl = LOG2R - dg * LOG2E - rm * KA;
  __syncthreads();
  // phase B: td -> exp+pack -> registers; denominator partial from unrounded e
  unsigned int pk0[17], pk1[17];
  float part = 0.f;
#pragma unroll
  for (int mt = 0; mt < 17; ++mt) {
    const bf16x8 p0 = *(const bf16x8*)&sm.sP[mt * 16 + r][q * 8];
    const bf16x8 p1 = *(const bf16x8*)&sm.sP[mt * 16 + r][32 + q * 8];
    f32x4 acc = (f32x4){0.f, 0.f, 0.f, 0.f};
    acc = MFMA16(p0, qb0, acc);
    acc = MFMA16(p1, qb1, acc);
    const f32x4 kl = *(const f32x4*)&ksuma[bh * MP3_ + mt * 16 + q * 4];
    {
      const float s0 = fminf(acc[0] * KA + Cl, LOG2R);
      const float s1 = fminf(acc[1] * KA + Cl, LOG2R);
      const float e0 = exp2f(s0) + REPS;
      const float e1 = exp2f(s1) + REPS;
      unsigned int pkk;
      asm("v_cvt_pk_bf16_f32 %0, %1, %2" : "=v"(pkk) : "v"(e0), "v"(e1));
      pk0[mt] = pkk;
      part += e0 * kl[0] + e1 * kl[1];
    }
    {
      const float s0 = fminf(acc[2] * KA + Cl, LOG2R);
      const float s1 = fminf(acc[3] * KA + Cl, LOG2R);
      const float e0 = exp2f(s0) + REPS;
      const float e1 = exp2f(s1) + REPS;
      unsigned int pkk;
      asm("v_cvt_pk_bf16_f32 %0, %1, %2" : "=v"(pkk) : "v"(e0), "v"(e1));
      pk1[mt] = pkk;
      part += e0 * kl[2] + e1 * kl[3];
    }
  }
  __syncthreads();  // all waves done reading sP; LDS becomes qps
  // dump packed qp regs -> wave-private qps tile (row r, u32 cols mt*8 + q*2)
#pragma unroll
  for (int mt = 0; mt < 17; ++mt)
    *(uint2*)&sm.qps[wv][r][mt * 8 + q * 2] = make_uint2(pk0[mt], pk1[mt]);
  // zero pad u32 cols 136..143 (bf16 cols 272..287)
  *(uint2*)&sm.qps[wv][r][136 + q * 2] = make_uint2(0u, 0u);
  part += __shfl_xor(part, 16, 64);
  part += __shfl_xor(part, 32, 64);
  const float dinv = 1.f / fmaxf(part, 1e-30f);
  // Phase C: out = qp . ctxT (K = 288); A-frags from wave-private LDS tile
  f32x4 oacc[4];
#pragma unroll
  for (int i = 0; i < 4; ++i) oacc[i] = (f32x4){0.f, 0.f, 0.f, 0.f};
  const unsigned short* cbase = ctxT + (size_t)bh * DH_ * MP2_;
#pragma unroll
  for (int kc = 0; kc < 9; ++kc) {
    const bf16x8 af = *(const bf16x8*)&sm.qps[wv][r][kc * 16 + q * 4];
#pragma unroll
    for (int dt = 0; dt < 4; ++dt) {
      const bf16x8 bfr = *(const bf16x8*)&cbase[(size_t)(dt * 16 + r) * MP2_ + kc * 32 + q * 8];
      oacc[dt] = MFMA16(af, bfr, oacc[dt]);
    }
  }
  // dinv lives at lane with r = n-local; output rows n-local = q*4+i
  float dv[4];
#pragma unroll
  for (int i = 0; i < 4; ++i)
    dv[i] = __shfl(dinv, (lane & 48) | (q * 4 + i), 64);
#pragma unroll
  for (int dt = 0; dt < 4; ++dt) {
    const int d = dt * 16 + r;
    unsigned short* abase = &attn[(size_t)(b_ * N_ + n0 + wv * 16 + q * 4) * DIM_ + h * DH_ + d];
#pragma unroll
    for (int p = 0; p < 2; ++p) {
      const float v0 = oacc[dt][2 * p] * dv[2 * p];
      const float v1 = oacc[dt][2 * p + 1] * dv[2 * p + 1];
      unsigned int pkk;
      asm("v_cvt_pk_bf16_f32 %0, %1, %2" : "=v"(pkk) : "v"(v0), "v"(v1));
      abase[(size_t)(2 * p) * DIM_] = (unsigned short)(pkk & 0xffffu);
      abase[(size_t)(2 * p + 1) * DIM_] = (unsigned short)(pkk >> 16);
    }
  }
}

// ---------------- final: 128x128 MFMA GEMM + residual, global_load_lds staging ----------------
__global__ __launch_bounds__(256) void final_mfma(
    const unsigned short* __restrict__ attn, const unsigned short* __restrict__ Wo,
    const float* __restrict__ bo, const float* __restrict__ x,
    float* __restrict__ out) {
  __shared__ unsigned short As[128 * 64];
  __shared__ unsigned short Bs[128 * 64];
  const int t0 = blockIdx.x * 128, e0 = blockIdx.y * 128;
  const int tid = threadIdx.x;
  const int wv = tid >> 6, lane = tid & 63;
  const int r = lane & 15, q = lane >> 4;
  const int wr = (wv >> 1) * 64, wc = (wv & 1) * 64;
  f32x4 acc[4][4];
#pragma unroll
  for (int i = 0; i < 4; ++i)
#pragma unroll
    for (int j = 0; j < 4; ++j) acc[i][j] = (f32x4){0.f, 0.f, 0.f, 0.f};
  const int lrow = lane >> 3, lcol = (lane & 7) * 8;
  for (int k0 = 0; k0 < DIM_; k0 += 64) {
#pragma unroll
    for (int j = 0; j < 4; ++j) {
      const int rr = wv * 32 + j * 8;
      gload16(&attn[(size_t)(t0 + rr + lrow) * DIM_ + k0 + lcol], &As[rr * 64]);
      gload16(&Wo[(size_t)(e0 + rr + lrow) * DIM_ + k0 + lcol], &Bs[rr * 64]);
    }
    __syncthreads();
#pragma unroll
    for (int kc = 0; kc < 2; ++kc) {
      bf16x8 af[4], bfr[4];
#pragma unroll
      for (int rt = 0; rt < 4; ++rt)
        af[rt] = *(const bf16x8*)&As[(wr + rt * 16 + r) * 64 + kc * 32 + q * 8];
#pragma unroll
      for (int ct = 0; ct < 4; ++ct)
        bfr[ct] = *(const bf16x8*)&Bs[(wc + ct * 16 + r) * 64 + kc * 32 + q * 8];
#pragma unroll
      for (int rt = 0; rt < 4; ++rt)
#pragma unroll
        for (int ct = 0; ct < 4; ++ct)
          acc[rt][ct] = MFMA16(af[rt], bfr[ct], acc[rt][ct]);
    }
    __syncthreads();
  }
#pragma unroll
  for (int rt = 0; rt < 4; ++rt) {
#pragma unroll
    for (int ct = 0; ct < 4; ++ct) {
      const int c = e0 + wc + ct * 16 + r;
      const float bov = bo[c];
#pragma unroll
      for (int i = 0; i < 4; ++i) {
        const int t = t0 + wr + rt * 16 + q * 4 + i;
        out[(size_t)t * DIM_ + c] = acc[rt][ct][i] + bov + x[(size_t)t * DIM_ + c];
      }
    }
  }
}

extern "C" void kernel_launch(void* const* d_in, const int* in_sizes, int n_in,
                              void* d_out, int out_size, void* d_ws, size_t ws_size,
                              hipStream_t stream) {
  const float* x = (const float*)d_in[0];
  const float* Wq = (const float*)d_in[1];
  const float* Wk = (const float*)d_in[2];
  const float* Wv = (const float*)d_in[3];
  const float* Wo = (const float*)d_in[4];
  const float* bo = (const float*)d_in[5];
  const float* proj = (const float*)d_in[6];
  char* ws = (char*)d_ws;
  unsigned short* projp = (unsigned short*)(ws + PROJP_B);
  float* kmax = (float*)(ws + KMAX_B);
  float* ksuma = (float*)(ws + KSUMA_B);
  float* ctxa = (float*)(ws + CTXA_B);
  unsigned short* ctxT = (unsigned short*)(ws + CTXT_B);
  unsigned short* diag_q = (unsigned short*)(ws + DIAGQ_B);
  unsigned short* diag_k = (unsigned short*)(ws + DIAGK_B);
  unsigned short* xbf = (unsigned short*)(ws + XBF_B);
  unsigned short* wqb = (unsigned short*)(ws + WQ_B);
  unsigned short* wkb = (unsigned short*)(ws + WK_B);
  unsigned short* wvb = (unsigned short*)(ws + WV_B);
  unsigned short* wob = (unsigned short*)(ws + WO_B);
  unsigned short* Q = (unsigned short*)(ws + Q_B);
  unsigned short* K = (unsigned short*)(ws + K_B);
  unsigned short* VT = (unsigned short*)(ws + VT_B);
  float* rmaxq = (float*)(ws + RMAXQ_B);
  unsigned short* attn = K;  // K dead after ctxfused_mfma
  float* out = (float*)d_out;

  prep_kernel<<<1024, 256, 0, stream>>>(x, Wq, Wk, Wv, Wo, proj,
                                        xbf, wqb, wkb, wvb, wob, projp, kmax, ksuma);
  qkv_mfma<<<dim3(NT_ / 128, DIM_ / 128), 256, 0, stream>>>(xbf, wqb, Q, VT, 0);
  qkv_mfma<<<dim3(NT_ / 128, DIM_ / 128), 256, 0, stream>>>(xbf, wkb, K, VT, 1);
  qkv_mfma<<<dim3(NT_ / 128, DIM_ / 128), 256, 0, stream>>>(xbf, wvb, Q, VT, 2);
  kmax_mfma<<<dim3(BH_, N_ / 256), 256, 0, stream>>>(K, Q, projp, kmax, rmaxq, diag_q, diag_k);
  ctxfused_mfma<<<dim3(BH_, 5, NZ_), 256, 0, stream>>>(K, VT, projp, diag_k, kmax, ksuma, ctxa);
  pack_kernel<<<dim3(BH_, 5), 256, 0, stream>>>(ctxa, ctxT);
  qpout_mfma<<<dim3(BH_, 64), 256, 0, stream>>>(Q, projp, rmaxq, diag_q, ksuma, ctxT, attn);
  final_mfma<<<dim3(NT_ / 128, DIM_ / 128), 256, 0, stream>>>(attn, wob, bo, x, out);
}

// Round 18
// 265.657 us; speedup vs baseline: 1.0247x; 1.0247x over previous
//
#include <hip/hip_runtime.h>

#define N_ 4096
#define DIM_ 512
#define H_ 8
#define DH_ 64
#define M_ 266
#define MP_ 272      // ksum/qp live range padded to 272 (17 tiles of 16)
#define MP2_ 288     // out-GEMM K padded to 9 chunks of 32
#define MP3_ 320     // ksuma / projp m padded to 5 chunks of 64
#define SLABM_ 280   // ctx partial-slab m extent (>= M_=266, trimmed to fit overlay)
#define NZ_ 8        // n-split for ctxfused
#define NT_ 16384
#define BH_ 32

#define NORMC 0.3535533905932738f   // 64^-0.25
#define RATIOC 0.06131393394849658f // 266^-0.5
#define EPSK 1e-4f
#define DIAGC 0.0625f               // 0.5 * normalizer^2
// folded exp2 constants: qp = exp2(min(raw*KA + Cl, LOG2R)) + REPS
#define KA 0.51006971f              // NORMC * log2(e)
#define LOG2R -4.0276408f           // log2(RATIOC)
#define LOG2E 1.4426950408889634f
#define REPS 6.131393e-6f           // RATIOC * EPSK

// ---- ws layout (byte offsets), total ~71.5 MB ----
// ctx slabs (18,350,080 B) overlay xbf+wqb+wkb+wvb, dead after qkv_mfma.
#define PROJP_B 0ul            // 40960
#define KMAX_B  40960ul        // 128
#define KSUMA_B 41088ul        // 40960
#define WO_B    82048ul        // 524288
#define CTXT_B  606336ul       // 1179648
#define DIAGQ_B 1785984ul      // 262144
#define DIAGK_B 2048128ul      // 262144
#define XBF_B   2310272ul      // 16777216
#define WQ_B    19087488ul     // 524288
#define WK_B    19611776ul     // 524288
#define WV_B    20136064ul     // 524288
#define CTXA_B  2310272ul      // == XBF_B, 32*8*280*64*4 = 18350080 (ends at Q_B)
#define Q_B     20660352ul     // 16777216
#define K_B     37437568ul     // 16777216
#define VT_B    54214784ul     // 16777216
#define RMAXQ_B 70992000ul     // 524288 (32*4096 f32) -> end 71,516,288

typedef __bf16 bf16x8 __attribute__((ext_vector_type(8)));
typedef float f32x4 __attribute__((ext_vector_type(4)));
#define MFMA16(a, b, c) __builtin_amdgcn_mfma_f32_16x16x32_bf16((a), (b), (c), 0, 0, 0)

// async global->LDS, 16B per lane; LDS dest = wave-uniform base + lane*16
typedef __attribute__((address_space(1))) const unsigned int* gas_t;
typedef __attribute__((address_space(3))) unsigned int* las_t;
__device__ __forceinline__ void gload16(const void* g, void* l) {
  __builtin_amdgcn_global_load_lds((gas_t)g, (las_t)l, 16, 0, 0);
}

__device__ __forceinline__ float bfu(unsigned short u) {
  union { unsigned int i; float f; } x; x.i = ((unsigned int)u) << 16; return x.f;
}
__device__ __forceinline__ unsigned short f2bf(float f) {
  union { float f; unsigned int i; } u; u.f = f;
  unsigned int r = u.i + 0x7fffu + ((u.i >> 16) & 1u);
  return (unsigned short)(r >> 16);
}
__device__ __forceinline__ void atomicMaxF(float* addr, float val) {
  int* ai = (int*)addr;
  while (true) {
    float cur = __int_as_float(*(volatile int*)ai);
    if (val <= cur) break;
    int old = atomicCAS(ai, __float_as_int(cur), __float_as_int(val));
    if (old == __float_as_int(cur)) break;
  }
}

// ---------------- prep: all fp32->bf16 conversions + proj pad + inits (1 launch) ----------------
__global__ void prep_kernel(const float* __restrict__ x, const float* __restrict__ Wq,
                            const float* __restrict__ Wk, const float* __restrict__ Wv,
                            const float* __restrict__ Wo, const float* __restrict__ proj,
                            unsigned short* __restrict__ xbf, unsigned short* __restrict__ wqb,
                            unsigned short* __restrict__ wkb, unsigned short* __restrict__ wvb,
                            unsigned short* __restrict__ wob,
                            unsigned short* __restrict__ projp,
                            float* __restrict__ kmax, float* __restrict__ ksuma) {
  const int t0 = blockIdx.x * 256 + threadIdx.x;
  const int stride = gridDim.x * 256;
  for (int i = t0; i < 8388608 / 4; i += stride) {
    const float4 v = ((const float4*)x)[i];
    ushort4 u;
    u.x = f2bf(v.x); u.y = f2bf(v.y); u.z = f2bf(v.z); u.w = f2bf(v.w);
    ((ushort4*)xbf)[i] = u;
  }
  const float* wsrc[4] = {Wq, Wk, Wv, Wo};
  unsigned short* wdst[4] = {wqb, wkb, wvb, wob};
#pragma unroll
  for (int w = 0; w < 4; ++w) {
    for (int i = t0; i < 262144 / 4; i += stride) {
      const float4 v = ((const float4*)wsrc[w])[i];
      ushort4 u;
      u.x = f2bf(v.x); u.y = f2bf(v.y); u.z = f2bf(v.z); u.w = f2bf(v.w);
      ((ushort4*)wdst[w])[i] = u;
    }
  }
  for (int j = t0; j < MP3_ * DH_; j += stride)
    projp[j] = (j < M_ * DH_) ? f2bf(proj[j]) : (unsigned short)0;
  for (int j = t0; j < BH_; j += stride) kmax[j] = -3e38f;
  for (int j = t0; j < BH_ * MP3_; j += stride) ksuma[j] = 0.f;
}

// ---------------- QKV projection: 128x128 MFMA GEMM, global_load_lds staging ----------------
// r7/r11-proven local optimum; z passed as ARG (3 dispatches) for profile visibility.
__global__ __launch_bounds__(256) void qkv_mfma(
    const unsigned short* __restrict__ x, const unsigned short* __restrict__ W,
    unsigned short* __restrict__ dstQK,  // Q (z=0) or K (z=1); unused for z=2
    unsigned short* __restrict__ VT,     // used for z=2
    const int z) {
  __shared__ unsigned short As[128 * 64];
  __shared__ unsigned short Bs[128 * 64];
  const int t0 = blockIdx.x * 128, e0 = blockIdx.y * 128;
  const int tid = threadIdx.x;
  const int wv = tid >> 6, lane = tid & 63;
  const int r = lane & 15, q = lane >> 4;
  const int wr = (wv >> 1) * 64, wc = (wv & 1) * 64;
  f32x4 acc[4][4];
#pragma unroll
  for (int i = 0; i < 4; ++i)
#pragma unroll
    for (int j = 0; j < 4; ++j) acc[i][j] = (f32x4){0.f, 0.f, 0.f, 0.f};
  // staging: wave wv covers rows wv*32 + j*8 + (lane>>3), col (lane&7)*8
  const int lrow = lane >> 3, lcol = (lane & 7) * 8;
  for (int k0 = 0; k0 < DIM_; k0 += 64) {
#pragma unroll
    for (int j = 0; j < 4; ++j) {
      const int rr = wv * 32 + j * 8;
      gload16(&x[(size_t)(t0 + rr + lrow) * DIM_ + k0 + lcol], &As[rr * 64]);
      gload16(&W[(size_t)(e0 + rr + lrow) * DIM_ + k0 + lcol], &Bs[rr * 64]);
    }
    __syncthreads();
#pragma unroll
    for (int kc = 0; kc < 2; ++kc) {
      bf16x8 af[4], bfr[4];
#pragma unroll
      for (int rt = 0; rt < 4; ++rt)
        af[rt] = *(const bf16x8*)&As[(wr + rt * 16 + r) * 64 + kc * 32 + q * 8];
#pragma unroll
      for (int ct = 0; ct < 4; ++ct)
        bfr[ct] = *(const bf16x8*)&Bs[(wc + ct * 16 + r) * 64 + kc * 32 + q * 8];
#pragma unroll
      for (int rt = 0; rt < 4; ++rt)
#pragma unroll
        for (int ct = 0; ct < 4; ++ct)
          acc[rt][ct] = MFMA16(af[rt], bfr[ct], acc[rt][ct]);
    }
    __syncthreads();
  }
  if (z < 2) {
    unsigned short* dst = dstQK;
#pragma unroll
    for (int rt = 0; rt < 4; ++rt) {
#pragma unroll
      for (int ct = 0; ct < 4; ++ct) {
        const int e = e0 + wc + ct * 16 + r;
#pragma unroll
        for (int i = 0; i < 4; ++i) {
          const int t = t0 + wr + rt * 16 + q * 4 + i;
          dst[(size_t)t * DIM_ + e] = f2bf(acc[rt][ct][i]);
        }
      }
    }
  } else {
#pragma unroll
    for (int rt = 0; rt < 4; ++rt) {
      const int t = t0 + wr + rt * 16 + q * 4;
      const int b_ = t >> 12, n = t & (N_ - 1);
#pragma unroll
      for (int ct = 0; ct < 4; ++ct) {
        const int e = e0 + wc + ct * 16 + r;
        const int h = e >> 6, dh = e & 63;
        ushort4 pk;
        pk.x = f2bf(acc[rt][ct][0]); pk.y = f2bf(acc[rt][ct][1]);
        pk.z = f2bf(acc[rt][ct][2]); pk.w = f2bf(acc[rt][ct][3]);
        *(ushort4*)&VT[((size_t)((b_ * H_ + h) * DH_ + dh)) * N_ + n] = pk;
      }
    }
  }
}

// ---------------- kmax/qmax (MFMA, merged) + diag: K global max, Q per-row max, diag_q/k ----------------
__global__ __launch_bounds__(256) void kmax_mfma(
    const unsigned short* __restrict__ K, const unsigned short* __restrict__ Qb,
    const unsigned short* __restrict__ projp,
    float* __restrict__ kmax, float* __restrict__ rmaxq,
    unsigned short* __restrict__ dq, unsigned short* __restrict__ dk) {
  __shared__ unsigned short sP[MP_][72];
  __shared__ float wm[4];
  const int bh = blockIdx.x, n0 = blockIdx.y * 256;
  const int tid = threadIdx.x;
  const int wv = tid >> 6, lane = tid & 63;
  const int r = lane & 15, q = lane >> 4;
  const int b_ = bh >> 3, h = bh & 7;
  // stage proj rows 0..271 (coalesced 16B chunks)
  for (int c = tid; c < MP_ * 4; c += 256) {
    const int row = c >> 2, cb = (c & 3) * 8;
    *(uint4*)&sP[row][cb] = *(const uint4*)&projp[row * DH_ + cb];
  }
  // load 4 K-strips + 4 Q-strips: rows nbase + st*16 + r
  bf16x8 kb[4][2], qb[4][2];
  const int nbase = n0 + wv * 64;
#pragma unroll
  for (int st = 0; st < 4; ++st) {
    const size_t off = (size_t)(b_ * N_ + nbase + st * 16 + r) * DIM_ + h * DH_;
    kb[st][0] = *(const bf16x8*)(K + off + q * 8);
    kb[st][1] = *(const bf16x8*)(K + off + 32 + q * 8);
    qb[st][0] = *(const bf16x8*)(Qb + off + q * 8);
    qb[st][1] = *(const bf16x8*)(Qb + off + 32 + q * 8);
  }
  // diag (merged): each lane holds 16 of the row's 64 values; q-butterfly completes the sum
#pragma unroll
  for (int st = 0; st < 4; ++st) {
    float sk = 0.f, sq = 0.f;
#pragma unroll
    for (int p = 0; p < 2; ++p)
#pragma unroll
      for (int e = 0; e < 8; ++e) {
        const float kv = (float)kb[st][p][e];
        const float qv = (float)qb[st][p][e];
        sk += kv * kv;
        sq += qv * qv;
      }
    sk += __shfl_xor(sk, 16, 64); sk += __shfl_xor(sk, 32, 64);
    sq += __shfl_xor(sq, 16, 64); sq += __shfl_xor(sq, 32, 64);
    if (q == 0) {
      dk[bh * N_ + nbase + st * 16 + r] = f2bf(sk * DIAGC);
      dq[bh * N_ + nbase + st * 16 + r] = f2bf(sq * DIAGC);
    }
  }
  __syncthreads();
  float km = -3e38f;
  float qm[4] = {-3e38f, -3e38f, -3e38f, -3e38f};
  for (int mt = 0; mt < 17; ++mt) {
    const bf16x8 p0 = *(const bf16x8*)&sP[mt * 16 + r][q * 8];
    const bf16x8 p1 = *(const bf16x8*)&sP[mt * 16 + r][32 + q * 8];
#pragma unroll
    for (int st = 0; st < 4; ++st) {
      f32x4 ka = (f32x4){0.f, 0.f, 0.f, 0.f};
      ka = MFMA16(p0, kb[st][0], ka);
      ka = MFMA16(p1, kb[st][1], ka);
      f32x4 qa = (f32x4){0.f, 0.f, 0.f, 0.f};
      qa = MFMA16(p0, qb[st][0], qa);
      qa = MFMA16(p1, qb[st][1], qa);
#pragma unroll
      for (int i = 0; i < 4; ++i) {
        const int m = mt * 16 + q * 4 + i;
        if (m < M_) {
          km = fmaxf(km, ka[i]);
          qm[st] = fmaxf(qm[st], qa[i]);
        }
      }
    }
  }
  // Q: per-row raw max -- combine the 4 q-groups (m coverage) per row
#pragma unroll
  for (int st = 0; st < 4; ++st) {
    float v = qm[st];
    v = fmaxf(v, __shfl_xor(v, 16, 64));
    v = fmaxf(v, __shfl_xor(v, 32, 64));
    if (q == 0) rmaxq[bh * N_ + nbase + st * 16 + r] = v;
  }
  // K: block max -> atomic
  for (int s2 = 1; s2 < 64; s2 <<= 1) km = fmaxf(km, __shfl_xor(km, s2, 64));
  if (lane == 0) wm[wv] = km;
  __syncthreads();
  if (tid == 0) {
    const float m = fmaxf(fmaxf(wm[0], wm[1]), fmaxf(wm[2], wm[3])) * NORMC;
    atomicMaxF(&kmax[bh], m);
  }
}

// ---------------- fused: td -> exp -> kp; ctx += kp x VT; ksum ----------------
// global_load_lds staging into LINEAR [64][64] kll/vtl; swapped-operand kp MFMA;
// packed kpl writes; exp2-folded constants.
__global__ __launch_bounds__(256) void ctxfused_mfma(
    const unsigned short* __restrict__ K, const unsigned short* __restrict__ VT,
    const unsigned short* __restrict__ projp, const unsigned short* __restrict__ diag_k,
    const float* __restrict__ kmaxv, float* __restrict__ ksuma,
    float* __restrict__ slab) {
  __shared__ unsigned short kll[64][64];
  __shared__ unsigned short vtl[64][64];
  __shared__ unsigned short kpl[64][72];
  __shared__ float dglC[64];
  const int bh = blockIdx.x, m0 = blockIdx.y * 64, zi = blockIdx.z;
  const int nbase = zi * 512;
  const int tid = threadIdx.x;
  const int wv = tid >> 6, lane = tid & 63;
  const int r = lane & 15, q = lane >> 4;
  const int b_ = bh >> 3, h = bh & 7;
  const float km = kmaxv[bh];
  const int m = m0 + wv * 16 + r;          // this lane's kp row
  const float msk = (m < M_) ? 1.f : 0.f;
  const unsigned short* prow = projp + (size_t)m * DH_;
  const bf16x8 p0 = *(const bf16x8*)(prow + q * 8);
  const bf16x8 p1 = *(const bf16x8*)(prow + 32 + q * 8);
  const unsigned short* kbase = K + (size_t)(b_ * N_) * DIM_ + h * DH_;
  const unsigned short* vbase = VT + (size_t)bh * DH_ * N_;
  f32x4 cacc[4];
#pragma unroll
  for (int i = 0; i < 4; ++i) cacc[i] = (f32x4){0.f, 0.f, 0.f, 0.f};
  float ksa = 0.f;
  // gload16 lane mapping: row base+l/8, elem col (l&7)*8 (rows are 128B linear)
  const int srow = lane >> 3, scol = (lane & 7) * 8;
  for (int nc = 0; nc < 8; ++nc) {
    const int n0c = nbase + nc * 64;
#pragma unroll
    for (int j = 0; j < 2; ++j) {
      const int rb = wv * 16 + j * 8;   // wave-uniform row base, 8 rows per issue
      gload16(&kbase[(size_t)(n0c + rb + srow) * DIM_ + scol], &kll[rb][0]);
      gload16(&vbase[(size_t)(rb + srow) * N_ + n0c + scol], &vtl[rb][0]);
    }
    if (tid < 16) {
      const ushort4 du = *(const ushort4*)&diag_k[bh * N_ + n0c + tid * 4];
      dglC[tid * 4 + 0] = LOG2R - (bfu(du.x) + km) * LOG2E;
      dglC[tid * 4 + 1] = LOG2R - (bfu(du.y) + km) * LOG2E;
      dglC[tid * 4 + 2] = LOG2R - (bfu(du.z) + km) * LOG2E;
      dglC[tid * 4 + 3] = LOG2R - (bfu(du.w) + km) * LOG2E;
    }
    __syncthreads();
#pragma unroll
    for (int nt = 0; nt < 4; ++nt) {
      const bf16x8 kb0 = *(const bf16x8*)&kll[nt * 16 + r][q * 8];
      const bf16x8 kb1 = *(const bf16x8*)&kll[nt * 16 + r][32 + q * 8];
      f32x4 acc = (f32x4){0.f, 0.f, 0.f, 0.f};
      acc = MFMA16(kb0, p0, acc);   // swapped: lane holds n = nt*16+q*4+i at m = wv*16+r
      acc = MFMA16(kb1, p1, acc);
      const f32x4 cl = *(const f32x4*)&dglC[nt * 16 + q * 4];
      float e0, e1, e2, e3;
      {
        const float s0 = fminf(acc[0] * KA + cl[0], LOG2R);
        const float s1 = fminf(acc[1] * KA + cl[1], LOG2R);
        const float s2 = fminf(acc[2] * KA + cl[2], LOG2R);
        const float s3 = fminf(acc[3] * KA + cl[3], LOG2R);
        e0 = msk * (exp2f(s0) + REPS);
        e1 = msk * (exp2f(s1) + REPS);
        e2 = msk * (exp2f(s2) + REPS);
        e3 = msk * (exp2f(s3) + REPS);
      }
      ksa += (e0 + e1) + (e2 + e3);
      unsigned int w0, w1;
      asm("v_cvt_pk_bf16_f32 %0, %1, %2" : "=v"(w0) : "v"(e0), "v"(e1));
      asm("v_cvt_pk_bf16_f32 %0, %1, %2" : "=v"(w1) : "v"(e2), "v"(e3));
      *(uint2*)&kpl[wv * 16 + r][nt * 16 + q * 4] = make_uint2(w0, w1);
    }
    __syncthreads();
    {
      const bf16x8 a0 = *(const bf16x8*)&kpl[wv * 16 + r][q * 8];
      const bf16x8 a1 = *(const bf16x8*)&kpl[wv * 16 + r][32 + q * 8];
#pragma unroll
      for (int ct = 0; ct < 4; ++ct) {
        const bf16x8 b0 = *(const bf16x8*)&vtl[ct * 16 + r][q * 8];
        const bf16x8 b1 = *(const bf16x8*)&vtl[ct * 16 + r][32 + q * 8];
        cacc[ct] = MFMA16(a0, b0, cacc[ct]);
        cacc[ct] = MFMA16(a1, b1, cacc[ct]);
      }
    }
    __syncthreads();
  }
  // ksa: lane holds partial over n in its q-group -> butterfly over q bits
  ksa += __shfl_xor(ksa, 16, 64);
  ksa += __shfl_xor(ksa, 32, 64);
  if (q == 0) atomicAdd(&ksuma[bh * MP3_ + m], ksa);
  float* sl = slab + (size_t)(bh * NZ_ + zi) * SLABM_ * DH_;
#pragma unroll
  for (int ct = 0; ct < 4; ++ct) {
#pragma unroll
    for (int i = 0; i < 4; ++i) {
      const int mm = m0 + wv * 16 + q * 4 + i;
      if (mm < SLABM_) sl[(size_t)mm * DH_ + ct * 16 + r] = cacc[ct][i];
    }
  }
}

// ---------------- pack: reduce 8 z-slabs [m][d] fp32 -> transpose -> ctxT [d][288] bf16 ----
__global__ __launch_bounds__(256) void pack_kernel(const float* __restrict__ slab,
                                                   unsigned short* __restrict__ ctxT) {
  __shared__ float t[64][65];
  const int bh = blockIdx.x, m0 = blockIdx.y * 64;
  const int tid = threadIdx.x;
  const int mr = tid >> 4, d4 = (tid & 15) * 4;
#pragma unroll
  for (int pass = 0; pass < 4; ++pass) {
    const int ml = pass * 16 + mr;
    const int m = m0 + ml;
    float4 s = {0.f, 0.f, 0.f, 0.f};
    if (m < SLABM_) {
#pragma unroll
      for (int z = 0; z < NZ_; ++z) {
        const float4 v =
            *(const float4*)&slab[((size_t)(bh * NZ_ + z) * SLABM_ + m) * DH_ + d4];
        s.x += v.x; s.y += v.y; s.z += v.z; s.w += v.w;
      }
    }
    t[ml][d4 + 0] = s.x; t[ml][d4 + 1] = s.y; t[ml][d4 + 2] = s.z; t[ml][d4 + 3] = s.w;
  }
  __syncthreads();
  const int mc = tid & 63, dbase = tid >> 6;
  const int mo = m0 + mc;
  if (mo < MP2_) {
#pragma unroll
    for (int j = 0; j < 16; ++j) {
      const int d = dbase + j * 4;
      ctxT[((size_t)bh * DH_ + d) * MP2_ + mo] = f2bf(t[mc][d]);
    }
  }
}

// ---------------- fused QP + out GEMM: proj LDS (union) + ctxT LDS (async prefetch) ----------------
// r17 A/B showed VALU and occupancy are NOT binding; the masker is phase C's 36
// per-lane L2 ctxT loads. Fix: stage the block's 64x288 ctxT tile into linear LDS
// via global_load_lds, ISSUED AFTER the first barrier so the transfer completes at
// the existing phase-B->C barrier (hidden under phase B). Phase C = pure ds_read+MFMA.
__global__ __launch_bounds__(256) void qpout_mfma(
    const unsigned short* __restrict__ Qb, const unsigned short* __restrict__ projp,
    const float* __restrict__ rmaxq,
    const unsigned short* __restrict__ diag_q, const float* __restrict__ ksuma,
    const unsigned short* __restrict__ ctxT, unsigned short* __restrict__ attn) {
  __shared__ union SM {
    unsigned short sP[MP_][72];      // 39168 B  (phase B)
    unsigned int qps[4][16][149];    // 38144 B  (phase C; per-wave tile, stride 149 u32)
  } sm;
  __shared__ unsigned short ctxl[64 * MP2_];  // 36864 B, staged async during phase B
  const int bh = blockIdx.x, n0 = blockIdx.y * 64;
  const int tid = threadIdx.x;
  const int wv = tid >> 6, lane = tid & 63;
  const int r = lane & 15, q = lane >> 4;
  const int b_ = bh >> 3, h = bh & 7;
  // stage proj rows 0..271 into sP (coalesced 16B chunks)
  for (int c = tid; c < MP_ * 4; c += 256) {
    const int row = c >> 2, cb = (c & 3) * 8;
    *(uint4*)&sm.sP[row][cb] = *(const uint4*)&projp[row * DH_ + cb];
  }
  bf16x8 qb0, qb1;
  {
    const unsigned short* qrow = Qb + (size_t)(b_ * N_ + n0 + wv * 16 + r) * DIM_ + h * DH_;
    qb0 = *(const bf16x8*)(qrow + q * 8);
    qb1 = *(const bf16x8*)(qrow + 32 + q * 8);
  }
  const float rm = rmaxq[bh * N_ + n0 + wv * 16 + r];
  const float dg = bfu(diag_q[bh * N_ + n0 + wv * 16 + r]);
  const float Cl = LOG2R - dg * LOG2E - rm * KA;
  __syncthreads();
  // issue ctxT tile stage (straight byte-copy, 9 x 1024B per wave); drains at next barrier
  {
    const char* gsrc = (const char*)(ctxT + (size_t)bh * DH_ * MP2_);
#pragma unroll
    for (int j = 0; j < 9; ++j) {
      const int off = wv * 9216 + j * 1024;
      gload16(gsrc + off + lane * 16, (char*)ctxl + off);
    }
  }
  // phase B: td -> exp+pack -> registers; denominator partial from unrounded e
  unsigned int pk0[17], pk1[17];
  float part = 0.f;
#pragma unroll
  for (int mt = 0; mt < 17; ++mt) {
    const bf16x8 p0 = *(const bf16x8*)&sm.sP[mt * 16 + r][q * 8];
    const bf16x8 p1 = *(const bf16x8*)&sm.sP[mt * 16 + r][32 + q * 8];
    f32x4 acc = (f32x4){0.f, 0.f, 0.f, 0.f};
    acc = MFMA16(p0, qb0, acc);
    acc = MFMA16(p1, qb1, acc);
    const f32x4 kl = *(const f32x4*)&ksuma[bh * MP3_ + mt * 16 + q * 4];
    {
      const float s0 = fminf(acc[0] * KA + Cl, LOG2R);
      const float s1 = fminf(acc[1] * KA + Cl, LOG2R);
      const float e0 = exp2f(s0) + REPS;
      const float e1 = exp2f(s1) + REPS;
      unsigned int pkk;
      asm("v_cvt_pk_bf16_f32 %0, %1, %2" : "=v"(pkk) : "v"(e0), "v"(e1));
      pk0[mt] = pkk;
      part += e0 * kl[0] + e1 * kl[1];
    }
    {
      const float s0 = fminf(acc[2] * KA + Cl, LOG2R);
      const float s1 = fminf(acc[3] * KA + Cl, LOG2R);
      const float e0 = exp2f(s0) + REPS;
      const float e1 = exp2f(s1) + REPS;
      unsigned int pkk;
      asm("v_cvt_pk_bf16_f32 %0, %1, %2" : "=v"(pkk) : "v"(e0), "v"(e1));
      pk1[mt] = pkk;
      part += e0 * kl[2] + e1 * kl[3];
    }
  }
  __syncthreads();  // sP done + vmcnt drained -> ctxl ready; LDS union becomes qps
  // dump packed qp regs -> wave-private qps tile (row r, u32 cols mt*8 + q*2)
#pragma unroll
  for (int mt = 0; mt < 17; ++mt)
    *(uint2*)&sm.qps[wv][r][mt * 8 + q * 2] = make_uint2(pk0[mt], pk1[mt]);
  // zero pad u32 cols 136..143 (bf16 cols 272..287)
  *(uint2*)&sm.qps[wv][r][136 + q * 2] = make_uint2(0u, 0u);
  part += __shfl_xor(part, 16, 64);
  part += __shfl_xor(part, 32, 64);
  const float dinv = 1.f / fmaxf(part, 1e-30f);
  // Phase C: out = qp . ctxT (K = 288); A-frags from qps, B-frags from ctxl (LDS)
  f32x4 oacc[4];
#pragma unroll
  for (int i = 0; i < 4; ++i) oacc[i] = (f32x4){0.f, 0.f, 0.f, 0.f};
#pragma unroll
  for (int kc = 0; kc < 9; ++kc) {
    const bf16x8 af = *(const bf16x8*)&sm.qps[wv][r][kc * 16 + q * 4];
#pragma unroll
    for (int dt = 0; dt < 4; ++dt) {
      const bf16x8 bfr = *(const bf16x8*)&ctxl[(dt * 16 + r) * MP2_ + kc * 32 + q * 8];
      oacc[dt] = MFMA16(af, bfr, oacc[dt]);
    }
  }
  // dinv lives at lane with r = n-local; output rows n-local = q*4+i
  float dv[4];
#pragma unroll
  for (int i = 0; i < 4; ++i)
    dv[i] = __shfl(dinv, (lane & 48) | (q * 4 + i), 64);
#pragma unroll
  for (int dt = 0; dt < 4; ++dt) {
    const int d = dt * 16 + r;
    unsigned short* abase = &attn[(size_t)(b_ * N_ + n0 + wv * 16 + q * 4) * DIM_ + h * DH_ + d];
#pragma unroll
    for (int p = 0; p < 2; ++p) {
      const float v0 = oacc[dt][2 * p] * dv[2 * p];
      const float v1 = oacc[dt][2 * p + 1] * dv[2 * p + 1];
      unsigned int pkk;
      asm("v_cvt_pk_bf16_f32 %0, %1, %2" : "=v"(pkk) : "v"(v0), "v"(v1));
      abase[(size_t)(2 * p) * DIM_] = (unsigned short)(pkk & 0xffffu);
      abase[(size_t)(2 * p + 1) * DIM_] = (unsigned short)(pkk >> 16);
    }
  }
}

// ---------------- final: 128x128 MFMA GEMM + residual, global_load_lds staging ----------------
__global__ __launch_bounds__(256) void final_mfma(
    const unsigned short* __restrict__ attn, const unsigned short* __restrict__ Wo,
    const float* __restrict__ bo, const float* __restrict__ x,
    float* __restrict__ out) {
  __shared__ unsigned short As[128 * 64];
  __shared__ unsigned short Bs[128 * 64];
  const int t0 = blockIdx.x * 128, e0 = blockIdx.y * 128;
  const int tid = threadIdx.x;
  const int wv = tid >> 6, lane = tid & 63;
  const int r = lane & 15, q = lane >> 4;
  const int wr = (wv >> 1) * 64, wc = (wv & 1) * 64;
  f32x4 acc[4][4];
#pragma unroll
  for (int i = 0; i < 4; ++i)
#pragma unroll
    for (int j = 0; j < 4; ++j) acc[i][j] = (f32x4){0.f, 0.f, 0.f, 0.f};
  const int lrow = lane >> 3, lcol = (lane & 7) * 8;
  for (int k0 = 0; k0 < DIM_; k0 += 64) {
#pragma unroll
    for (int j = 0; j < 4; ++j) {
      const int rr = wv * 32 + j * 8;
      gload16(&attn[(size_t)(t0 + rr + lrow) * DIM_ + k0 + lcol], &As[rr * 64]);
      gload16(&Wo[(size_t)(e0 + rr + lrow) * DIM_ + k0 + lcol], &Bs[rr * 64]);
    }
    __syncthreads();
#pragma unroll
    for (int kc = 0; kc < 2; ++kc) {
      bf16x8 af[4], bfr[4];
#pragma unroll
      for (int rt = 0; rt < 4; ++rt)
        af[rt] = *(const bf16x8*)&As[(wr + rt * 16 + r) * 64 + kc * 32 + q * 8];
#pragma unroll
      for (int ct = 0; ct < 4; ++ct)
        bfr[ct] = *(const bf16x8*)&Bs[(wc + ct * 16 + r) * 64 + kc * 32 + q * 8];
#pragma unroll
      for (int rt = 0; rt < 4; ++rt)
#pragma unroll
        for (int ct = 0; ct < 4; ++ct)
          acc[rt][ct] = MFMA16(af[rt], bfr[ct], acc[rt][ct]);
    }
    __syncthreads();
  }
#pragma unroll
  for (int rt = 0; rt < 4; ++rt) {
#pragma unroll
    for (int ct = 0; ct < 4; ++ct) {
      const int c = e0 + wc + ct * 16 + r;
      const float bov = bo[c];
#pragma unroll
      for (int i = 0; i < 4; ++i) {
        const int t = t0 + wr + rt * 16 + q * 4 + i;
        out[(size_t)t * DIM_ + c] = acc[rt][ct][i] + bov + x[(size_t)t * DIM_ + c];
      }
    }
  }
}

extern "C" void kernel_launch(void* const* d_in, const int* in_sizes, int n_in,
                              void* d_out, int out_size, void* d_ws, size_t ws_size,
                              hipStream_t stream) {
  const float* x = (const float*)d_in[0];
  const float* Wq = (const float*)d_in[1];
  const float* Wk = (const float*)d_in[2];
  const float* Wv = (const float*)d_in[3];
  const float* Wo = (const float*)d_in[4];
  const float* bo = (const float*)d_in[5];
  const float* proj = (const float*)d_in[6];
  char* ws = (char*)d_ws;
  unsigned short* projp = (unsigned short*)(ws + PROJP_B);
  float* kmax = (float*)(ws + KMAX_B);
  float* ksuma = (float*)(ws + KSUMA_B);
  float* ctxa = (float*)(ws + CTXA_B);
  unsigned short* ctxT = (unsigned short*)(ws + CTXT_B);
  unsigned short* diag_q = (unsigned short*)(ws + DIAGQ_B);
  unsigned short* diag_k = (unsigned short*)(ws + DIAGK_B);
  unsigned short* xbf = (unsigned short*)(ws + XBF_B);
  unsigned short* wqb = (unsigned short*)(ws + WQ_B);
  unsigned short* wkb = (unsigned short*)(ws + WK_B);
  unsigned short* wvb = (unsigned short*)(ws + WV_B);
  unsigned short* wob = (unsigned short*)(ws + WO_B);
  unsigned short* Q = (unsigned short*)(ws + Q_B);
  unsigned short* K = (unsigned short*)(ws + K_B);
  unsigned short* VT = (unsigned short*)(ws + VT_B);
  float* rmaxq = (float*)(ws + RMAXQ_B);
  unsigned short* attn = K;  // K dead after ctxfused_mfma
  float* out = (float*)d_out;

  prep_kernel<<<1024, 256, 0, stream>>>(x, Wq, Wk, Wv, Wo, proj,
                                        xbf, wqb, wkb, wvb, wob, projp, kmax, ksuma);
  qkv_mfma<<<dim3(NT_ / 128, DIM_ / 128), 256, 0, stream>>>(xbf, wqb, Q, VT, 0);
  qkv_mfma<<<dim3(NT_ / 128, DIM_ / 128), 256, 0, stream>>>(xbf, wkb, K, VT, 1);
  qkv_mfma<<<dim3(NT_ / 128, DIM_ / 128), 256, 0, stream>>>(xbf, wvb, Q, VT, 2);
  kmax_mfma<<<dim3(BH_, N_ / 256), 256, 0, stream>>>(K, Q, projp, kmax, rmaxq, diag_q, diag_k);
  ctxfused_mfma<<<dim3(BH_, 5, NZ_), 256, 0, stream>>>(K, VT, projp, diag_k, kmax, ksuma, ctxa);
  pack_kernel<<<dim3(BH_, 5), 256, 0, stream>>>(ctxa, ctxT);
  qpout_mfma<<<dim3(BH_, 64), 256, 0, stream>>>(Q, projp, rmaxq, diag_q, ksuma, ctxT, attn);
  final_mfma<<<dim3(NT_ / 128, DIM_ / 128), 256, 0, stream>>>(attn, wob, bo, x, out);
}

// Round 19
// 260.225 us; speedup vs baseline: 1.0461x; 1.0209x over previous
//
#include <hip/hip_runtime.h>

#define N_ 4096
#define DIM_ 512
#define H_ 8
#define DH_ 64
#define M_ 266
#define MP_ 272      // ksum/qp live range padded to 272 (17 tiles of 16)
#define MP2_ 288     // out-GEMM K padded to 9 chunks of 32
#define MP3_ 320     // ksuma / projp m padded to 5 chunks of 64
#define SLABM_ 280   // ctx partial-slab m extent (>= M_=266, trimmed to fit overlay)
#define NZ_ 8        // n-split for ctxfused
#define NT_ 16384
#define BH_ 32

#define NORMC 0.3535533905932738f   // 64^-0.25
#define RATIOC 0.06131393394849658f // 266^-0.5
#define EPSK 1e-4f
#define DIAGC 0.0625f               // 0.5 * normalizer^2
// folded exp2 constants: qp = exp2(min(raw*KA + Cl, LOG2R)) + REPS
#define KA 0.51006971f              // NORMC * log2(e)
#define LOG2R -4.0276408f           // log2(RATIOC)
#define LOG2E 1.4426950408889634f
#define REPS 6.131393e-6f           // RATIOC * EPSK

// ---- ws layout (byte offsets), total ~71.5 MB ----
// ctx slabs (18,350,080 B) overlay xbf+wqb+wkb+wvb, dead after qkv_mfma.
#define PROJP_B 0ul            // 40960
#define KMAX_B  40960ul        // 128
#define KSUMA_B 41088ul        // 40960
#define WO_B    82048ul        // 524288
#define CTXT_B  606336ul       // 1179648
#define DIAGQ_B 1785984ul      // 262144
#define DIAGK_B 2048128ul      // 262144
#define XBF_B   2310272ul      // 16777216
#define WQ_B    19087488ul     // 524288
#define WK_B    19611776ul     // 524288
#define WV_B    20136064ul     // 524288
#define CTXA_B  2310272ul      // == XBF_B, 32*8*280*64*4 = 18350080 (ends at Q_B)
#define Q_B     20660352ul     // 16777216
#define K_B     37437568ul     // 16777216
#define VT_B    54214784ul     // 16777216
#define RMAXQ_B 70992000ul     // 524288 (32*4096 f32) -> end 71,516,288

typedef __bf16 bf16x8 __attribute__((ext_vector_type(8)));
typedef float f32x4 __attribute__((ext_vector_type(4)));
#define MFMA16(a, b, c) __builtin_amdgcn_mfma_f32_16x16x32_bf16((a), (b), (c), 0, 0, 0)

// async global->LDS, 16B per lane; LDS dest = wave-uniform base + lane*16
typedef __attribute__((address_space(1))) const unsigned int* gas_t;
typedef __attribute__((address_space(3))) unsigned int* las_t;
__device__ __forceinline__ void gload16(const void* g, void* l) {
  __builtin_amdgcn_global_load_lds((gas_t)g, (las_t)l, 16, 0, 0);
}

__device__ __forceinline__ float bfu(unsigned short u) {
  union { unsigned int i; float f; } x; x.i = ((unsigned int)u) << 16; return x.f;
}
__device__ __forceinline__ unsigned short f2bf(float f) {
  union { float f; unsigned int i; } u; u.f = f;
  unsigned int r = u.i + 0x7fffu + ((u.i >> 16) & 1u);
  return (unsigned short)(r >> 16);
}
__device__ __forceinline__ void atomicMaxF(float* addr, float val) {
  int* ai = (int*)addr;
  while (true) {
    float cur = __int_as_float(*(volatile int*)ai);
    if (val <= cur) break;
    int old = atomicCAS(ai, __float_as_int(cur), __float_as_int(val));
    if (old == __float_as_int(cur)) break;
  }
}

// ---------------- prep: all fp32->bf16 conversions + proj pad + inits (1 launch) ----------------
__global__ void prep_kernel(const float* __restrict__ x, const float* __restrict__ Wq,
                            const float* __restrict__ Wk, const float* __restrict__ Wv,
                            const float* __restrict__ Wo, const float* __restrict__ proj,
                            unsigned short* __restrict__ xbf, unsigned short* __restrict__ wqb,
                            unsigned short* __restrict__ wkb, unsigned short* __restrict__ wvb,
                            unsigned short* __restrict__ wob,
                            unsigned short* __restrict__ projp,
                            float* __restrict__ kmax, float* __restrict__ ksuma) {
  const int t0 = blockIdx.x * 256 + threadIdx.x;
  const int stride = gridDim.x * 256;
  for (int i = t0; i < 8388608 / 4; i += stride) {
    const float4 v = ((const float4*)x)[i];
    ushort4 u;
    u.x = f2bf(v.x); u.y = f2bf(v.y); u.z = f2bf(v.z); u.w = f2bf(v.w);
    ((ushort4*)xbf)[i] = u;
  }
  const float* wsrc[4] = {Wq, Wk, Wv, Wo};
  unsigned short* wdst[4] = {wqb, wkb, wvb, wob};
#pragma unroll
  for (int w = 0; w < 4; ++w) {
    for (int i = t0; i < 262144 / 4; i += stride) {
      const float4 v = ((const float4*)wsrc[w])[i];
      ushort4 u;
      u.x = f2bf(v.x); u.y = f2bf(v.y); u.z = f2bf(v.z); u.w = f2bf(v.w);
      ((ushort4*)wdst[w])[i] = u;
    }
  }
  for (int j = t0; j < MP3_ * DH_; j += stride)
    projp[j] = (j < M_ * DH_) ? f2bf(proj[j]) : (unsigned short)0;
  for (int j = t0; j < BH_; j += stride) kmax[j] = -3e38f;
  for (int j = t0; j < BH_ * MP3_; j += stride) ksuma[j] = 0.f;
}

// ---------------- QKV projection: 128x128 MFMA GEMM, global_load_lds staging (merged z) ----------------
__global__ __launch_bounds__(256) void qkv_mfma(
    const unsigned short* __restrict__ x, const unsigned short* __restrict__ Wq,
    const unsigned short* __restrict__ Wk, const unsigned short* __restrict__ Wv,
    unsigned short* __restrict__ Q, unsigned short* __restrict__ K,
    unsigned short* __restrict__ VT) {
  __shared__ unsigned short As[128 * 64];
  __shared__ unsigned short Bs[128 * 64];
  const int z = blockIdx.z;
  const unsigned short* W = (z == 0) ? Wq : (z == 1) ? Wk : Wv;
  const int t0 = blockIdx.x * 128, e0 = blockIdx.y * 128;
  const int tid = threadIdx.x;
  const int wv = tid >> 6, lane = tid & 63;
  const int r = lane & 15, q = lane >> 4;
  const int wr = (wv >> 1) * 64, wc = (wv & 1) * 64;
  f32x4 acc[4][4];
#pragma unroll
  for (int i = 0; i < 4; ++i)
#pragma unroll
    for (int j = 0; j < 4; ++j) acc[i][j] = (f32x4){0.f, 0.f, 0.f, 0.f};
  // staging: wave wv covers rows wv*32 + j*8 + (lane>>3), col (lane&7)*8
  const int lrow = lane >> 3, lcol = (lane & 7) * 8;
  for (int k0 = 0; k0 < DIM_; k0 += 64) {
#pragma unroll
    for (int j = 0; j < 4; ++j) {
      const int rr = wv * 32 + j * 8;
      gload16(&x[(size_t)(t0 + rr + lrow) * DIM_ + k0 + lcol], &As[rr * 64]);
      gload16(&W[(size_t)(e0 + rr + lrow) * DIM_ + k0 + lcol], &Bs[rr * 64]);
    }
    __syncthreads();
#pragma unroll
    for (int kc = 0; kc < 2; ++kc) {
      bf16x8 af[4], bfr[4];
#pragma unroll
      for (int rt = 0; rt < 4; ++rt)
        af[rt] = *(const bf16x8*)&As[(wr + rt * 16 + r) * 64 + kc * 32 + q * 8];
#pragma unroll
      for (int ct = 0; ct < 4; ++ct)
        bfr[ct] = *(const bf16x8*)&Bs[(wc + ct * 16 + r) * 64 + kc * 32 + q * 8];
#pragma unroll
      for (int rt = 0; rt < 4; ++rt)
#pragma unroll
        for (int ct = 0; ct < 4; ++ct)
          acc[rt][ct] = MFMA16(af[rt], bfr[ct], acc[rt][ct]);
    }
    __syncthreads();
  }
  if (z < 2) {
    unsigned short* dst = (z == 0) ? Q : K;
#pragma unroll
    for (int rt = 0; rt < 4; ++rt) {
#pragma unroll
      for (int ct = 0; ct < 4; ++ct) {
        const int e = e0 + wc + ct * 16 + r;
#pragma unroll
        for (int i = 0; i < 4; ++i) {
          const int t = t0 + wr + rt * 16 + q * 4 + i;
          dst[(size_t)t * DIM_ + e] = f2bf(acc[rt][ct][i]);
        }
      }
    }
  } else {
#pragma unroll
    for (int rt = 0; rt < 4; ++rt) {
      const int t = t0 + wr + rt * 16 + q * 4;
      const int b_ = t >> 12, n = t & (N_ - 1);
#pragma unroll
      for (int ct = 0; ct < 4; ++ct) {
        const int e = e0 + wc + ct * 16 + r;
        const int h = e >> 6, dh = e & 63;
        ushort4 pk;
        pk.x = f2bf(acc[rt][ct][0]); pk.y = f2bf(acc[rt][ct][1]);
        pk.z = f2bf(acc[rt][ct][2]); pk.w = f2bf(acc[rt][ct][3]);
        *(ushort4*)&VT[((size_t)((b_ * H_ + h) * DH_ + dh)) * N_ + n] = pk;
      }
    }
  }
}

// ---------------- kmax/qmax (MFMA, merged) + diag: K global max, Q per-row max, diag_q/k ----------------
__global__ __launch_bounds__(256) void kmax_mfma(
    const unsigned short* __restrict__ K, const unsigned short* __restrict__ Qb,
    const unsigned short* __restrict__ projp,
    float* __restrict__ kmax, float* __restrict__ rmaxq,
    unsigned short* __restrict__ dq, unsigned short* __restrict__ dk) {
  __shared__ unsigned short sP[MP_][72];
  __shared__ float wm[4];
  const int bh = blockIdx.x, n0 = blockIdx.y * 256;
  const int tid = threadIdx.x;
  const int wv = tid >> 6, lane = tid & 63;
  const int r = lane & 15, q = lane >> 4;
  const int b_ = bh >> 3, h = bh & 7;
  // stage proj rows 0..271 (coalesced 16B chunks)
  for (int c = tid; c < MP_ * 4; c += 256) {
    const int row = c >> 2, cb = (c & 3) * 8;
    *(uint4*)&sP[row][cb] = *(const uint4*)&projp[row * DH_ + cb];
  }
  // load 4 K-strips + 4 Q-strips: rows nbase + st*16 + r
  bf16x8 kb[4][2], qb[4][2];
  const int nbase = n0 + wv * 64;
#pragma unroll
  for (int st = 0; st < 4; ++st) {
    const size_t off = (size_t)(b_ * N_ + nbase + st * 16 + r) * DIM_ + h * DH_;
    kb[st][0] = *(const bf16x8*)(K + off + q * 8);
    kb[st][1] = *(const bf16x8*)(K + off + 32 + q * 8);
    qb[st][0] = *(const bf16x8*)(Qb + off + q * 8);
    qb[st][1] = *(const bf16x8*)(Qb + off + 32 + q * 8);
  }
  // diag (merged): each lane holds 16 of the row's 64 values; q-butterfly completes the sum
#pragma unroll
  for (int st = 0; st < 4; ++st) {
    float sk = 0.f, sq = 0.f;
#pragma unroll
    for (int p = 0; p < 2; ++p)
#pragma unroll
      for (int e = 0; e < 8; ++e) {
        const float kv = (float)kb[st][p][e];
        const float qv = (float)qb[st][p][e];
        sk += kv * kv;
        sq += qv * qv;
      }
    sk += __shfl_xor(sk, 16, 64); sk += __shfl_xor(sk, 32, 64);
    sq += __shfl_xor(sq, 16, 64); sq += __shfl_xor(sq, 32, 64);
    if (q == 0) {
      dk[bh * N_ + nbase + st * 16 + r] = f2bf(sk * DIAGC);
      dq[bh * N_ + nbase + st * 16 + r] = f2bf(sq * DIAGC);
    }
  }
  __syncthreads();
  float km = -3e38f;
  float qm[4] = {-3e38f, -3e38f, -3e38f, -3e38f};
  for (int mt = 0; mt < 17; ++mt) {
    const bf16x8 p0 = *(const bf16x8*)&sP[mt * 16 + r][q * 8];
    const bf16x8 p1 = *(const bf16x8*)&sP[mt * 16 + r][32 + q * 8];
#pragma unroll
    for (int st = 0; st < 4; ++st) {
      f32x4 ka = (f32x4){0.f, 0.f, 0.f, 0.f};
      ka = MFMA16(p0, kb[st][0], ka);
      ka = MFMA16(p1, kb[st][1], ka);
      f32x4 qa = (f32x4){0.f, 0.f, 0.f, 0.f};
      qa = MFMA16(p0, qb[st][0], qa);
      qa = MFMA16(p1, qb[st][1], qa);
#pragma unroll
      for (int i = 0; i < 4; ++i) {
        const int m = mt * 16 + q * 4 + i;
        if (m < M_) {
          km = fmaxf(km, ka[i]);
          qm[st] = fmaxf(qm[st], qa[i]);
        }
      }
    }
  }
  // Q: per-row raw max -- combine the 4 q-groups (m coverage) per row
#pragma unroll
  for (int st = 0; st < 4; ++st) {
    float v = qm[st];
    v = fmaxf(v, __shfl_xor(v, 16, 64));
    v = fmaxf(v, __shfl_xor(v, 32, 64));
    if (q == 0) rmaxq[bh * N_ + nbase + st * 16 + r] = v;
  }
  // K: block max -> atomic
  for (int s2 = 1; s2 < 64; s2 <<= 1) km = fmaxf(km, __shfl_xor(km, s2, 64));
  if (lane == 0) wm[wv] = km;
  __syncthreads();
  if (tid == 0) {
    const float m = fmaxf(fmaxf(wm[0], wm[1]), fmaxf(wm[2], wm[3])) * NORMC;
    atomicMaxF(&kmax[bh], m);
  }
}

// ---------------- fused: td -> exp -> kp; ctx += kp x VT; ksum ----------------
// global_load_lds staging into LINEAR [64][64] kll/vtl; swapped-operand kp MFMA;
// packed kpl writes; exp2-folded constants.
__global__ __launch_bounds__(256) void ctxfused_mfma(
    const unsigned short* __restrict__ K, const unsigned short* __restrict__ VT,
    const unsigned short* __restrict__ projp, const unsigned short* __restrict__ diag_k,
    const float* __restrict__ kmaxv, float* __restrict__ ksuma,
    float* __restrict__ slab) {
  __shared__ unsigned short kll[64][64];
  __shared__ unsigned short vtl[64][64];
  __shared__ unsigned short kpl[64][72];
  __shared__ float dglC[64];
  const int bh = blockIdx.x, m0 = blockIdx.y * 64, zi = blockIdx.z;
  const int nbase = zi * 512;
  const int tid = threadIdx.x;
  const int wv = tid >> 6, lane = tid & 63;
  const int r = lane & 15, q = lane >> 4;
  const int b_ = bh >> 3, h = bh & 7;
  const float km = kmaxv[bh];
  const int m = m0 + wv * 16 + r;          // this lane's kp row
  const float msk = (m < M_) ? 1.f : 0.f;
  const unsigned short* prow = projp + (size_t)m * DH_;
  const bf16x8 p0 = *(const bf16x8*)(prow + q * 8);
  const bf16x8 p1 = *(const bf16x8*)(prow + 32 + q * 8);
  const unsigned short* kbase = K + (size_t)(b_ * N_) * DIM_ + h * DH_;
  const unsigned short* vbase = VT + (size_t)bh * DH_ * N_;
  f32x4 cacc[4];
#pragma unroll
  for (int i = 0; i < 4; ++i) cacc[i] = (f32x4){0.f, 0.f, 0.f, 0.f};
  float ksa = 0.f;
  // gload16 lane mapping: row base+l/8, elem col (l&7)*8 (rows are 128B linear)
  const int srow = lane >> 3, scol = (lane & 7) * 8;
  for (int nc = 0; nc < 8; ++nc) {
    const int n0c = nbase + nc * 64;
#pragma unroll
    for (int j = 0; j < 2; ++j) {
      const int rb = wv * 16 + j * 8;   // wave-uniform row base, 8 rows per issue
      gload16(&kbase[(size_t)(n0c + rb + srow) * DIM_ + scol], &kll[rb][0]);
      gload16(&vbase[(size_t)(rb + srow) * N_ + n0c + scol], &vtl[rb][0]);
    }
    if (tid < 16) {
      const ushort4 du = *(const ushort4*)&diag_k[bh * N_ + n0c + tid * 4];
      dglC[tid * 4 + 0] = LOG2R - (bfu(du.x) + km) * LOG2E;
      dglC[tid * 4 + 1] = LOG2R - (bfu(du.y) + km) * LOG2E;
      dglC[tid * 4 + 2] = LOG2R - (bfu(du.z) + km) * LOG2E;
      dglC[tid * 4 + 3] = LOG2R - (bfu(du.w) + km) * LOG2E;
    }
    __syncthreads();
#pragma unroll
    for (int nt = 0; nt < 4; ++nt) {
      const bf16x8 kb0 = *(const bf16x8*)&kll[nt * 16 + r][q * 8];
      const bf16x8 kb1 = *(const bf16x8*)&kll[nt * 16 + r][32 + q * 8];
      f32x4 acc = (f32x4){0.f, 0.f, 0.f, 0.f};
      acc = MFMA16(kb0, p0, acc);   // swapped: lane holds n = nt*16+q*4+i at m = wv*16+r
      acc = MFMA16(kb1, p1, acc);
      const f32x4 cl = *(const f32x4*)&dglC[nt * 16 + q * 4];
      float e0, e1, e2, e3;
      {
        const float s0 = fminf(acc[0] * KA + cl[0], LOG2R);
        const float s1 = fminf(acc[1] * KA + cl[1], LOG2R);
        const float s2 = fminf(acc[2] * KA + cl[2], LOG2R);
        const float s3 = fminf(acc[3] * KA + cl[3], LOG2R);
        e0 = msk * (exp2f(s0) + REPS);
        e1 = msk * (exp2f(s1) + REPS);
        e2 = msk * (exp2f(s2) + REPS);
        e3 = msk * (exp2f(s3) + REPS);
      }
      ksa += (e0 + e1) + (e2 + e3);
      unsigned int w0, w1;
      asm("v_cvt_pk_bf16_f32 %0, %1, %2" : "=v"(w0) : "v"(e0), "v"(e1));
      asm("v_cvt_pk_bf16_f32 %0, %1, %2" : "=v"(w1) : "v"(e2), "v"(e3));
      *(uint2*)&kpl[wv * 16 + r][nt * 16 + q * 4] = make_uint2(w0, w1);
    }
    __syncthreads();
    {
      const bf16x8 a0 = *(const bf16x8*)&kpl[wv * 16 + r][q * 8];
      const bf16x8 a1 = *(const bf16x8*)&kpl[wv * 16 + r][32 + q * 8];
#pragma unroll
      for (int ct = 0; ct < 4; ++ct) {
        const bf16x8 b0 = *(const bf16x8*)&vtl[ct * 16 + r][q * 8];
        const bf16x8 b1 = *(const bf16x8*)&vtl[ct * 16 + r][32 + q * 8];
        cacc[ct] = MFMA16(a0, b0, cacc[ct]);
        cacc[ct] = MFMA16(a1, b1, cacc[ct]);
      }
    }
    __syncthreads();
  }
  // ksa: lane holds partial over n in its q-group -> butterfly over q bits
  ksa += __shfl_xor(ksa, 16, 64);
  ksa += __shfl_xor(ksa, 32, 64);
  if (q == 0) atomicAdd(&ksuma[bh * MP3_ + m], ksa);
  float* sl = slab + (size_t)(bh * NZ_ + zi) * SLABM_ * DH_;
#pragma unroll
  for (int ct = 0; ct < 4; ++ct) {
#pragma unroll
    for (int i = 0; i < 4; ++i) {
      const int mm = m0 + wv * 16 + q * 4 + i;
      if (mm < SLABM_) sl[(size_t)mm * DH_ + ct * 16 + r] = cacc[ct][i];
    }
  }
}

// ---------------- pack: reduce 8 z-slabs [m][d] fp32 -> transpose -> ctxT [d][288] bf16 ----
__global__ __launch_bounds__(256) void pack_kernel(const float* __restrict__ slab,
                                                   unsigned short* __restrict__ ctxT) {
  __shared__ float t[64][65];
  const int bh = blockIdx.x, m0 = blockIdx.y * 64;
  const int tid = threadIdx.x;
  const int mr = tid >> 4, d4 = (tid & 15) * 4;
#pragma unroll
  for (int pass = 0; pass < 4; ++pass) {
    const int ml = pass * 16 + mr;
    const int m = m0 + ml;
    float4 s = {0.f, 0.f, 0.f, 0.f};
    if (m < SLABM_) {
#pragma unroll
      for (int z = 0; z < NZ_; ++z) {
        const float4 v =
            *(const float4*)&slab[((size_t)(bh * NZ_ + z) * SLABM_ + m) * DH_ + d4];
        s.x += v.x; s.y += v.y; s.z += v.z; s.w += v.w;
      }
    }
    t[ml][d4 + 0] = s.x; t[ml][d4 + 1] = s.y; t[ml][d4 + 2] = s.z; t[ml][d4 + 3] = s.w;
  }
  __syncthreads();
  const int mc = tid & 63, dbase = tid >> 6;
  const int mo = m0 + mc;
  if (mo < MP2_) {
#pragma unroll
    for (int j = 0; j < 16; ++j) {
      const int d = dbase + j * 4;
      ctxT[((size_t)bh * DH_ + d) * MP2_ + mo] = f2bf(t[mc][d]);
    }
  }
}

// ---------------- fused QP + out GEMM: proj LDS (union) + ctxT LDS (async prefetch) ----------------
__global__ __launch_bounds__(256) void qpout_mfma(
    const unsigned short* __restrict__ Qb, const unsigned short* __restrict__ projp,
    const float* __restrict__ rmaxq,
    const unsigned short* __restrict__ diag_q, const float* __restrict__ ksuma,
    const unsigned short* __restrict__ ctxT, unsigned short* __restrict__ attn) {
  __shared__ union SM {
    unsigned short sP[MP_][72];      // 39168 B  (phase B)
    unsigned int qps[4][16][149];    // 38144 B  (phase C; per-wave tile, stride 149 u32)
  } sm;
  __shared__ unsigned short ctxl[64 * MP2_];  // 36864 B, staged async during phase B
  const int bh = blockIdx.x, n0 = blockIdx.y * 64;
  const int tid = threadIdx.x;
  const int wv = tid >> 6, lane = tid & 63;
  const int r = lane & 15, q = lane >> 4;
  const int b_ = bh >> 3, h = bh & 7;
  // stage proj rows 0..271 into sP (coalesced 16B chunks)
  for (int c = tid; c < MP_ * 4; c += 256) {
    const int row = c >> 2, cb = (c & 3) * 8;
    *(uint4*)&sm.sP[row][cb] = *(const uint4*)&projp[row * DH_ + cb];
  }
  bf16x8 qb0, qb1;
  {
    const unsigned short* qrow = Qb + (size_t)(b_ * N_ + n0 + wv * 16 + r) * DIM_ + h * DH_;
    qb0 = *(const bf16x8*)(qrow + q * 8);
    qb1 = *(const bf16x8*)(qrow + 32 + q * 8);
  }
  const float rm = rmaxq[bh * N_ + n0 + wv * 16 + r];
  const float dg = bfu(diag_q[bh * N_ + n0 + wv * 16 + r]);
  const float Cl = LOG2R - dg * LOG2E - rm * KA;
  __syncthreads();
  // issue ctxT tile stage (straight byte-copy, 9 x 1024B per wave); drains at next barrier
  {
    const char* gsrc = (const char*)(ctxT + (size_t)bh * DH_ * MP2_);
#pragma unroll
    for (int j = 0; j < 9; ++j) {
      const int off = wv * 9216 + j * 1024;
      gload16(gsrc + off + lane * 16, (char*)ctxl + off);
    }
  }
  // phase B: td -> exp+pack -> registers; denominator partial from unrounded e
  unsigned int pk0[17], pk1[17];
  float part = 0.f;
#pragma unroll
  for (int mt = 0; mt < 17; ++mt) {
    const bf16x8 p0 = *(const bf16x8*)&sm.sP[mt * 16 + r][q * 8];
    const bf16x8 p1 = *(const bf16x8*)&sm.sP[mt * 16 + r][32 + q * 8];
    f32x4 acc = (f32x4){0.f, 0.f, 0.f, 0.f};
    acc = MFMA16(p0, qb0, acc);
    acc = MFMA16(p1, qb1, acc);
    const f32x4 kl = *(const f32x4*)&ksuma[bh * MP3_ + mt * 16 + q * 4];
    {
      const float s0 = fminf(acc[0] * KA + Cl, LOG2R);
      const float s1 = fminf(acc[1] * KA + Cl, LOG2R);
      const float e0 = exp2f(s0) + REPS;
      const float e1 = exp2f(s1) + REPS;
      unsigned int pkk;
      asm("v_cvt_pk_bf16_f32 %0, %1, %2" : "=v"(pkk) : "v"(e0), "v"(e1));
      pk0[mt] = pkk;
      part += e0 * kl[0] + e1 * kl[1];
    }
    {
      const float s0 = fminf(acc[2] * KA + Cl, LOG2R);
      const float s1 = fminf(acc[3] * KA + Cl, LOG2R);
      const float e0 = exp2f(s0) + REPS;
      const float e1 = exp2f(s1) + REPS;
      unsigned int pkk;
      asm("v_cvt_pk_bf16_f32 %0, %1, %2" : "=v"(pkk) : "v"(e0), "v"(e1));
      pk1[mt] = pkk;
      part += e0 * kl[2] + e1 * kl[3];
    }
  }
  __syncthreads();  // sP done + vmcnt drained -> ctxl ready; LDS union becomes qps
  // dump packed qp regs -> wave-private qps tile (row r, u32 cols mt*8 + q*2)
#pragma unroll
  for (int mt = 0; mt < 17; ++mt)
    *(uint2*)&sm.qps[wv][r][mt * 8 + q * 2] = make_uint2(pk0[mt], pk1[mt]);
  // zero pad u32 cols 136..143 (bf16 cols 272..287)
  *(uint2*)&sm.qps[wv][r][136 + q * 2] = make_uint2(0u, 0u);
  part += __shfl_xor(part, 16, 64);
  part += __shfl_xor(part, 32, 64);
  const float dinv = 1.f / fmaxf(part, 1e-30f);
  // Phase C: out = qp . ctxT (K = 288); A-frags from qps, B-frags from ctxl (LDS)
  f32x4 oacc[4];
#pragma unroll
  for (int i = 0; i < 4; ++i) oacc[i] = (f32x4){0.f, 0.f, 0.f, 0.f};
#pragma unroll
  for (int kc = 0; kc < 9; ++kc) {
    const bf16x8 af = *(const bf16x8*)&sm.qps[wv][r][kc * 16 + q * 4];
#pragma unroll
    for (int dt = 0; dt < 4; ++dt) {
      const bf16x8 bfr = *(const bf16x8*)&ctxl[(dt * 16 + r) * MP2_ + kc * 32 + q * 8];
      oacc[dt] = MFMA16(af, bfr, oacc[dt]);
    }
  }
  // dinv lives at lane with r = n-local; output rows n-local = q*4+i
  float dv[4];
#pragma unroll
  for (int i = 0; i < 4; ++i)
    dv[i] = __shfl(dinv, (lane & 48) | (q * 4 + i), 64);
#pragma unroll
  for (int dt = 0; dt < 4; ++dt) {
    const int d = dt * 16 + r;
    unsigned short* abase = &attn[(size_t)(b_ * N_ + n0 + wv * 16 + q * 4) * DIM_ + h * DH_ + d];
#pragma unroll
    for (int p = 0; p < 2; ++p) {
      const float v0 = oacc[dt][2 * p] * dv[2 * p];
      const float v1 = oacc[dt][2 * p + 1] * dv[2 * p + 1];
      unsigned int pkk;
      asm("v_cvt_pk_bf16_f32 %0, %1, %2" : "=v"(pkk) : "v"(v0), "v"(v1));
      abase[(size_t)(2 * p) * DIM_] = (unsigned short)(pkk & 0xffffu);
      abase[(size_t)(2 * p + 1) * DIM_] = (unsigned short)(pkk >> 16);
    }
  }
}

// ---------------- final: 128x128 MFMA GEMM + residual, global_load_lds staging ----------------
__global__ __launch_bounds__(256) void final_mfma(
    const unsigned short* __restrict__ attn, const unsigned short* __restrict__ Wo,
    const float* __restrict__ bo, const float* __restrict__ x,
    float* __restrict__ out) {
  __shared__ unsigned short As[128 * 64];
  __shared__ unsigned short Bs[128 * 64];
  const int t0 = blockIdx.x * 128, e0 = blockIdx.y * 128;
  const int tid = threadIdx.x;
  const int wv = tid >> 6, lane = tid & 63;
  const int r = lane & 15, q = lane >> 4;
  const int wr = (wv >> 1) * 64, wc = (wv & 1) * 64;
  f32x4 acc[4][4];
#pragma unroll
  for (int i = 0; i < 4; ++i)
#pragma unroll
    for (int j = 0; j < 4; ++j) acc[i][j] = (f32x4){0.f, 0.f, 0.f, 0.f};
  const int lrow = lane >> 3, lcol = (lane & 7) * 8;
  for (int k0 = 0; k0 < DIM_; k0 += 64) {
#pragma unroll
    for (int j = 0; j < 4; ++j) {
      const int rr = wv * 32 + j * 8;
      gload16(&attn[(size_t)(t0 + rr + lrow) * DIM_ + k0 + lcol], &As[rr * 64]);
      gload16(&Wo[(size_t)(e0 + rr + lrow) * DIM_ + k0 + lcol], &Bs[rr * 64]);
    }
    __syncthreads();
#pragma unroll
    for (int kc = 0; kc < 2; ++kc) {
      bf16x8 af[4], bfr[4];
#pragma unroll
      for (int rt = 0; rt < 4; ++rt)
        af[rt] = *(const bf16x8*)&As[(wr + rt * 16 + r) * 64 + kc * 32 + q * 8];
#pragma unroll
      for (int ct = 0; ct < 4; ++ct)
        bfr[ct] = *(const bf16x8*)&Bs[(wc + ct * 16 + r) * 64 + kc * 32 + q * 8];
#pragma unroll
      for (int rt = 0; rt < 4; ++rt)
#pragma unroll
        for (int ct = 0; ct < 4; ++ct)
          acc[rt][ct] = MFMA16(af[rt], bfr[ct], acc[rt][ct]);
    }
    __syncthreads();
  }
#pragma unroll
  for (int rt = 0; rt < 4; ++rt) {
#pragma unroll
    for (int ct = 0; ct < 4; ++ct) {
      const int c = e0 + wc + ct * 16 + r;
      const float bov = bo[c];
#pragma unroll
      for (int i = 0; i < 4; ++i) {
        const int t = t0 + wr + rt * 16 + q * 4 + i;
        out[(size_t)t * DIM_ + c] = acc[rt][ct][i] + bov + x[(size_t)t * DIM_ + c];
      }
    }
  }
}

extern "C" void kernel_launch(void* const* d_in, const int* in_sizes, int n_in,
                              void* d_out, int out_size, void* d_ws, size_t ws_size,
                              hipStream_t stream) {
  const float* x = (const float*)d_in[0];
  const float* Wq = (const float*)d_in[1];
  const float* Wk = (const float*)d_in[2];
  const float* Wv = (const float*)d_in[3];
  const float* Wo = (const float*)d_in[4];
  const float* bo = (const float*)d_in[5];
  const float* proj = (const float*)d_in[6];
  char* ws = (char*)d_ws;
  unsigned short* projp = (unsigned short*)(ws + PROJP_B);
  float* kmax = (float*)(ws + KMAX_B);
  float* ksuma = (float*)(ws + KSUMA_B);
  float* ctxa = (float*)(ws + CTXA_B);
  unsigned short* ctxT = (unsigned short*)(ws + CTXT_B);
  unsigned short* diag_q = (unsigned short*)(ws + DIAGQ_B);
  unsigned short* diag_k = (unsigned short*)(ws + DIAGK_B);
  unsigned short* xbf = (unsigned short*)(ws + XBF_B);
  unsigned short* wqb = (unsigned short*)(ws + WQ_B);
  unsigned short* wkb = (unsigned short*)(ws + WK_B);
  unsigned short* wvb = (unsigned short*)(ws + WV_B);
  unsigned short* wob = (unsigned short*)(ws + WO_B);
  unsigned short* Q = (unsigned short*)(ws + Q_B);
  unsigned short* K = (unsigned short*)(ws + K_B);
  unsigned short* VT = (unsigned short*)(ws + VT_B);
  float* rmaxq = (float*)(ws + RMAXQ_B);
  unsigned short* attn = K;  // K dead after ctxfused_mfma
  float* out = (float*)d_out;

  prep_kernel<<<1024, 256, 0, stream>>>(x, Wq, Wk, Wv, Wo, proj,
                                        xbf, wqb, wkb, wvb, wob, projp, kmax, ksuma);
  qkv_mfma<<<dim3(NT_ / 128, DIM_ / 128, 3), 256, 0, stream>>>(xbf, wqb, wkb, wvb, Q, K, VT);
  kmax_mfma<<<dim3(BH_, N_ / 256), 256, 0, stream>>>(K, Q, projp, kmax, rmaxq, diag_q, diag_k);
  ctxfused_mfma<<<dim3(BH_, 5, NZ_), 256, 0, stream>>>(K, VT, projp, diag_k, kmax, ksuma, ctxa);
  pack_kernel<<<dim3(BH_, 5), 256, 0, stream>>>(ctxa, ctxT);
  qpout_mfma<<<dim3(BH_, 64), 256, 0, stream>>>(Q, projp, rmaxq, diag_q, ksuma, ctxT, attn);
  final_mfma<<<dim3(NT_ / 128, DIM_ / 128), 256, 0, stream>>>(attn, wob, bo, x, out);
}